// Round 10
// baseline (355.829 us; speedup 1.0000x reference)
//
#include <hip/hip_runtime.h>
#include <hip/hip_bf16.h>
#include <math.h>

#define BN 8
#define AN 15
#define HH 100
#define WW 168
#define HW (HH*WW)           // 16800
#define NPI (AN*HW)          // 252000 scores per image
#define NTOT (BN*NPI)        // 2016000
#define PRE 2000
#define POST 1000
#define CAP 4096             // candidate buffer per image (threshold-bucket bound ~3000)
#define ROWW 32              // u64 words per NMS mask row (2000 bits -> 32 words)
#define NCHUNK 32            // ceil(PRE/64)
#define RSTRIDE 2048         // padded per-image row stride
#define EPB 4096             // elements per hist block
#define HBLK 62              // ceil(NPI/EPB)

typedef unsigned int u32;
typedef unsigned long long u64;

// ---- workspace layout (bytes) ----
#define OFF_H1     0            // 8*256*4 = 8192
#define OFF_H2     8192         // 8192
#define OFF_CSTAR  16384        // 8*128 = 1024 (cstar[b*32], base[b*32+1])
#define OFF_CCNT   17408        // 1024
#define OFF_THR    18432        // 1024
#define OFF_CAND   19456        // 8*4096*8 = 262144
#define OFF_BOX    281600       // 8*2048*16 = 262144
#define OFF_SCORE  543744       // 65536
#define OFF_VALID  609280       // 65536
#define OFF_MASK   674816       // 8*2048*32*8 = 4194304
#define OFF_DIAG   4869120      // 8*2048*8 = 131072 (packed diagonal words)
#define ZERO_WORDS ((OFF_CAND) / 4)   // only hist/counters need zeroing

__device__ __forceinline__ u32 fmono(float s) {
  u32 u = __float_as_uint(s);
  return (u & 0x80000000u) ? ~u : (u | 0x80000000u);
}
__device__ __forceinline__ float funmono(u32 m) {
  u32 u = (m & 0x80000000u) ? (m ^ 0x80000000u) : ~m;
  return __uint_as_float(u);
}
__device__ __forceinline__ float areaf(float4 bx) {
  return __fmul_rn(__fadd_rn(__fsub_rn(bx.z, bx.x), 1.0f),
                   __fadd_rn(__fsub_rn(bx.w, bx.y), 1.0f));
}

__global__ void zero_kernel(u32* p, int n) {
  int i = blockIdx.x * blockDim.x + threadIdx.x;
  if (i < n) p[i] = 0u;
}

// phase-1 histogram: 256 coarse buckets (m>>24), LDS-privatized 4-way
__global__ __launch_bounds__(256) void hist1_kernel(const float* __restrict__ cls,
                                                    u32* __restrict__ h1) {
  __shared__ u32 lh[1024];   // 4 copies x 256 buckets
  int b = blockIdx.y;
  int t = threadIdx.x;
  for (int q = t; q < 1024; q += 256) lh[q] = 0u;
  __syncthreads();
  int start = blockIdx.x * EPB;
  int end = min(start + EPB, NPI);
  const float* p = cls + (size_t)b * NPI;
  u32 copy = ((u32)t & 3u) << 8;
  for (int i = start + t; i < end; i += 256) {
    u32 m = fmono(p[i]);
    atomicAdd(&lh[copy | (m >> 24)], 1u);
  }
  __syncthreads();
  u32 s = lh[t] + lh[t + 256] + lh[t + 512] + lh[t + 768];
  if (s) atomicAdd(&h1[(b << 8) + t], s);
}

// pick coarse bucket c*: suffix scan of 256 coarse counts
__global__ __launch_bounds__(256) void coarse_kernel(const u32* __restrict__ h1,
                                                     u32* __restrict__ cstar) {
  int b = blockIdx.x;
  int t = threadIdx.x;
  __shared__ u32 sfx[256];
  sfx[t] = h1[(b << 8) + t];
  __syncthreads();
  for (int d = 1; d < 256; d <<= 1) {
    u32 add = (t + d < 256) ? sfx[t + d] : 0u;
    __syncthreads();
    sfx[t] += add;
    __syncthreads();
  }
  if (t == 0 && sfx[0] < (u32)PRE) { cstar[b * 32] = 0u; cstar[b * 32 + 1] = sfx[1]; }
  if (sfx[t] >= (u32)PRE && (t == 255 || sfx[t + 1] < (u32)PRE)) {
    cstar[b * 32] = (u32)t;
    cstar[b * 32 + 1] = (t == 255) ? 0u : sfx[t + 1];   // count strictly above c*
  }
}

// phase-2 histogram: 256 fine buckets ((m>>16)&0xFF), filtered to m>>24==c*
__global__ __launch_bounds__(256) void hist2_kernel(const float* __restrict__ cls,
                                                    const u32* __restrict__ cstar,
                                                    u32* __restrict__ h2) {
  __shared__ u32 lh[256];
  int b = blockIdx.y;
  int t = threadIdx.x;
  lh[t] = 0u;
  __syncthreads();
  u32 cs = cstar[b * 32];
  int start = blockIdx.x * EPB;
  int end = min(start + EPB, NPI);
  const float* p = cls + (size_t)b * NPI;
  for (int i = start + t; i < end; i += 256) {
    u32 m = fmono(p[i]);
    if ((m >> 24) == cs) atomicAdd(&lh[(m >> 16) & 0xFFu], 1u);
  }
  __syncthreads();
  if (lh[t]) atomicAdd(&h2[(b << 8) + t], lh[t]);
}

// final 16-bit threshold: thr16 = (c*<<8) | k*, largest k with base+sfx[k] >= PRE
__global__ __launch_bounds__(256) void fine_kernel(const u32* __restrict__ h2,
                                                   const u32* __restrict__ cstar,
                                                   u32* __restrict__ thr) {
  int b = blockIdx.x;
  int t = threadIdx.x;
  __shared__ u32 sfx[256];
  sfx[t] = h2[(b << 8) + t];
  __syncthreads();
  for (int d = 1; d < 256; d <<= 1) {
    u32 add = (t + d < 256) ? sfx[t + d] : 0u;
    __syncthreads();
    sfx[t] += add;
    __syncthreads();
  }
  u32 cs = cstar[b * 32], base = cstar[b * 32 + 1];
  if (t == 0 && base + sfx[0] < (u32)PRE) thr[b * 32] = (cs << 8);
  if (base + sfx[t] >= (u32)PRE && (t == 255 || base + sfx[t + 1] < (u32)PRE))
    thr[b * 32] = (cs << 8) | (u32)t;
}

// wave-aggregated gather: one atomic per wave with >=1 candidate
__global__ void gather_kernel(const float* __restrict__ cls, const u32* __restrict__ thr,
                              u32* __restrict__ ccnt, u64* __restrict__ cand) {
  int tid = blockIdx.x * blockDim.x + threadIdx.x;   // grid exactly covers NTOT
  int b = tid / NPI;
  int r = tid - b * NPI;
  u32 m = fmono(cls[tid]);
  bool pass = (m >> 16) >= thr[b * 32];
  int lane = threadIdx.x & 63;
  int b0 = __shfl(b, 0, 64);
  bool uni = (__ballot(b != b0) == 0ULL);
  u32 pos = 0xffffffffu;
  if (uni) {
    u64 bal = __ballot(pass);
    if (bal) {
      int leader = __ffsll((long long)bal) - 1;
      u32 base = 0;
      if (lane == leader) base = atomicAdd(&ccnt[b * 32], (u32)__popcll(bal));
      base = __shfl(base, leader, 64);
      if (pass) pos = base + (u32)__popcll(bal & ((1ULL << lane) - 1ULL));
    }
  } else if (pass) {
    pos = atomicAdd(&ccnt[b * 32], 1u);
  }
  if (pass && pos < CAP) {
    int a  = r / HW;
    int hw = r - a * HW;
    u32 i  = (u32)(hw * AN + a);   // transposed flat index (h*W + w)*A + a
    cand[(size_t)b * CAP + pos] = ((u64)m << 32) | (u32)(~i);
  }
}

__global__ __launch_bounds__(1024) void sort_transform_kernel(
    const u64* __restrict__ cand, const u32* __restrict__ ccnt,
    const float* __restrict__ bbox, const float* __restrict__ iminfo,
    const float* __restrict__ anch,
    float4* __restrict__ boxes, float* __restrict__ scores, int* __restrict__ valid) {
  __shared__ u64 keys[CAP];   // 32 KB
  int b = blockIdx.x;
  int t = threadIdx.x;
  u32 cnt = ccnt[b * 32];
  if (cnt > CAP) cnt = CAP;
  for (int q = t; q < CAP; q += 1024) keys[q] = (q < (int)cnt) ? cand[(size_t)b * CAP + q] : 0ULL;
  __syncthreads();
  // bitonic sort, descending
  for (u32 k = 2; k <= CAP; k <<= 1) {
    for (u32 j = k >> 1; j > 0; j >>= 1) {
      for (int p = 0; p < CAP / 2 / 1024; ++p) {
        u32 idx = (u32)t + (u32)p * 1024u;           // 0..CAP/2-1
        u32 base = ((idx & ~(j - 1)) << 1) | (idx & (j - 1));
        u32 partner = base + j;
        bool up = ((base & k) == 0);
        u64 A = keys[base], B = keys[partner];
        bool sw = up ? (A < B) : (A > B);
        if (sw) { keys[base] = B; keys[partner] = A; }
      }
      __syncthreads();
    }
  }
  // transform the top PRE
  float im_h = iminfo[b * 3 + 0], im_w = iminfo[b * 3 + 1], im_s = iminfo[b * 3 + 2];
  float wmax = __fsub_rn(im_w, 1.0f), hmax = __fsub_rn(im_h, 1.0f);
  float msz = __fmul_rn(0.0f, im_s);
  const float BCLIP = (float)4.135166556742356;  // log(1000/16)
  for (int q = t; q < PRE; q += 1024) {
    u64 key = keys[q];
    u32 i = ~((u32)key);
    // defensive: pad keys (q >= cnt) decode to i >= NPI -> never dereference
    if (q >= (int)cnt || i >= (u32)NPI) {
      boxes[b * RSTRIDE + q] = make_float4(0.f, 0.f, 0.f, 0.f);
      scores[b * RSTRIDE + q] = 0.f;
      valid[b * RSTRIDE + q] = 0;
      continue;
    }
    float sc = funmono((u32)(key >> 32));
    int a = (int)(i % AN);
    int pp = (int)(i / AN);
    int w = pp % WW;
    int h = pp / WW;
    float sx = (float)(w * 8), sy = (float)(h * 8);
    float ax1 = __fadd_rn(anch[a * 4 + 0], sx);
    float ay1 = __fadd_rn(anch[a * 4 + 1], sy);
    float ax2 = __fadd_rn(anch[a * 4 + 2], sx);
    float ay2 = __fadd_rn(anch[a * 4 + 3], sy);
    float wsA = __fadd_rn(__fsub_rn(ax2, ax1), 1.0f);
    float hsA = __fadd_rn(__fsub_rn(ay2, ay1), 1.0f);
    float cx = __fadd_rn(ax1, __fmul_rn(0.5f, wsA));
    float cy = __fadd_rn(ay1, __fmul_rn(0.5f, hsA));
    const float* dp = bbox + ((size_t)b * (4 * AN) + 4 * a) * HW + (size_t)h * WW + w;
    float dx = dp[0], dy = dp[HW], dwv = dp[2 * HW], dhv = dp[3 * HW];
    dwv = fminf(dwv, BCLIP);
    dhv = fminf(dhv, BCLIP);
    float pcx = __fadd_rn(__fmul_rn(dx, wsA), cx);
    float pcy = __fadd_rn(__fmul_rn(dy, hsA), cy);
    float pw = __fmul_rn((float)exp((double)dwv), wsA);
    float ph = __fmul_rn((float)exp((double)dhv), hsA);
    float hpw = __fmul_rn(0.5f, pw), hph = __fmul_rn(0.5f, ph);
    float x1 = __fsub_rn(pcx, hpw);
    float y1 = __fsub_rn(pcy, hph);
    float x2 = __fsub_rn(__fadd_rn(pcx, hpw), 1.0f);
    float y2 = __fsub_rn(__fadd_rn(pcy, hph), 1.0f);
    x1 = fminf(fmaxf(x1, 0.0f), wmax);
    y1 = fminf(fmaxf(y1, 0.0f), hmax);
    x2 = fminf(fmaxf(x2, 0.0f), wmax);
    y2 = fminf(fmaxf(y2, 0.0f), hmax);
    float ws2 = __fadd_rn(__fsub_rn(x2, x1), 1.0f);
    float hs2 = __fadd_rn(__fsub_rn(y2, y1), 1.0f);
    int v = (ws2 >= msz) && (hs2 >= msz) &&
            (__fadd_rn(x1, __fmul_rn(ws2, 0.5f)) < im_w) &&
            (__fadd_rn(y1, __fmul_rn(hs2, 0.5f)) < im_h);
    boxes[b * RSTRIDE + q] = make_float4(x1, y1, x2, y2);
    scores[b * RSTRIDE + q] = sc;
    valid[b * RSTRIDE + q] = v;
  }
}

__global__ __launch_bounds__(64) void nms_mask_kernel(const float4* __restrict__ boxes,
                                                      u64* __restrict__ mask,
                                                      u64* __restrict__ diag) {
  int jb = blockIdx.x, ib = blockIdx.y, b = blockIdx.z;
  if (jb < ib) return;   // upper triangle only (j > i needed)
  int t = threadIdx.x;
  __shared__ float4 jbox[64];
  __shared__ float jarea[64];
  int jbase = jb * 64;
  int jcount = min(64, PRE - jbase);
  if (t < jcount) {
    float4 bj = boxes[b * RSTRIDE + jbase + t];
    jbox[t] = bj;
    jarea[t] = areaf(bj);
  }
  __syncthreads();
  int i = ib * 64 + t;
  if (i >= PRE) return;
  float4 bi = boxes[b * RSTRIDE + i];
  float ai = areaf(bi);
  u64 word = 0ULL;
  for (int jj = 0; jj < jcount; ++jj) {
    int j = jbase + jj;
    if (j <= i) continue;
    float4 bj = jbox[jj];
    float iw = fmaxf(__fadd_rn(__fsub_rn(fminf(bi.z, bj.z), fmaxf(bi.x, bj.x)), 1.0f), 0.0f);
    float ih = fmaxf(__fadd_rn(__fsub_rn(fminf(bi.w, bj.w), fmaxf(bi.y, bj.y)), 1.0f), 0.0f);
    float inter = __fmul_rn(iw, ih);
    float denom = __fsub_rn(__fadd_rn(ai, jarea[jj]), inter);
    float iou = inter / denom;
    if (iou > 0.7f) word |= (1ULL << jj);
  }
  mask[((size_t)(b * RSTRIDE) + i) * ROWW + jb] = word;
  if (jb == ib) diag[(size_t)b * RSTRIDE + i] = word;   // packed diagonal word
}

// ---------------- seq NMS v7: v6 + batched fold ----------------
// R9 postmortem: 112us = 64*32*~120cyc -- the fold's ds_reads serialized
// at full LDS latency because `rem |=` forms one dependency chain the
// compiler won't pipeline loads across. v7 loads 16 rows into an explicit
// temp array (independent ds_read_b64 -> batched issue, one wait), then
// masked-ORs into 4 rotating accumulators (no serial chain in a group).
__device__ __forceinline__ void stage_chunk(const void* gsrc, void* lds, int lane) {
#pragma unroll
  for (int k = 0; k < 16; ++k) {
    const char* g = (const char*)gsrc + k * 1024 + lane * 16;
    char* l = (char*)lds + k * 1024;   // HW dest = uniform base + lane*16
    __builtin_amdgcn_global_load_lds(
        (const __attribute__((address_space(1))) unsigned int*)g,
        (__attribute__((address_space(3))) unsigned int*)l, 16, 0, 0);
  }
}

__global__ __launch_bounds__(64) void seq_nms_kernel(
    const u64* __restrict__ mask, const u64* __restrict__ diag,
    const int* __restrict__ valid,
    const float4* __restrict__ boxes, const float* __restrict__ scores,
    float* __restrict__ out) {
  int b = blockIdx.x;
  int lane = threadIdx.x;
  int lw = lane & 31;
  __shared__ u64 rowbuf[2][64 * ROWW];   // 2 x 16 KB double buffer
  __shared__ u64 vbuf[NCHUNK];
  __shared__ u64 kbits_s[NCHUNK];
  __shared__ int chunkoff[NCHUNK];
  __shared__ int keeplist[PRE];
  __shared__ int Ksh;

  // precompute per-chunk valid ballots into LDS (unrolled: static v[] index)
  {
    int v[NCHUNK];
#pragma unroll
    for (int c = 0; c < NCHUNK; ++c) {
      int q = c * 64 + lane;
      v[c] = (q < PRE) ? valid[b * RSTRIDE + q] : 0;
    }
#pragma unroll
    for (int c = 0; c < NCHUNK; ++c) {
      u64 bl = __ballot(v[c] != 0);
      if (lane == 0) vbuf[c] = bl;
    }
  }

  const u64* base = mask + (size_t)b * RSTRIDE * ROWW;
  const u64* dg = diag + (size_t)b * RSTRIDE;

  stage_chunk(base, rowbuf[0], lane);     // chunk 0

  u64 rem = 0ULL, cur = 0ULL;
  for (int c = 0; c < NCHUNK; ++c) {
    // prefetch next chunk (independent; overlaps everything below)
    if (c + 1 < NCHUNK) stage_chunk(base + (size_t)(c + 1) * 64 * ROWW,
                                    rowbuf[(c + 1) & 1], lane);
    // wave-uniform valid mask, rescalarized
    u64 vbv = vbuf[c];
    u32 vlo = (u32)__builtin_amdgcn_readfirstlane((int)(u32)vbv);
    u32 vhi = (u32)__builtin_amdgcn_readfirstlane((int)(u32)(vbv >> 32));
    u64 vb = ((u64)vhi << 32) | vlo;
    // scalar serial chain over the chunk's diagonal words
    const u64* dgc = dg + c * 64;
    u64 cl = cur;
#pragma unroll
    for (int ii = 0; ii < 64; ++ii) {
      u64 D = dgc[ii];                     // uniform -> s_load (merged x16)
      u64 t = ((~cl & vb) >> ii) & 1ULL;
      cl |= t ? D : 0ULL;                  // s_cselect_b64 + s_or_b64
    }
    u64 keepb = vb & ~cl;
    // drain previous chunk's staging; keep the 16 prefetch loads in flight
    if (c + 1 < NCHUNK) __builtin_amdgcn_s_waitcnt(0x4F70);   // vmcnt(16)
    else                __builtin_amdgcn_s_waitcnt(0x0F70);   // vmcnt(0)
    // batched fold: groups of 16 independent ds_read_b64, then masked ORs
    // into 4 rotating accumulators (no serial chain within a group)
    const u64* rb = rowbuf[c & 1];
    u64 acc0 = 0ULL, acc1 = 0ULL, acc2 = 0ULL, acc3 = 0ULL;
#pragma unroll
    for (int g = 0; g < 4; ++g) {
      u64 t[16];
#pragma unroll
      for (int j = 0; j < 16; ++j) t[j] = rb[(g * 16 + j) * ROWW + lw];
#pragma unroll
      for (int j = 0; j < 16; ++j) {
        int ii = g * 16 + j;
        u64 km = 0ULL - ((keepb >> ii) & 1ULL);
        u64 v = t[j] & km;
        if ((j & 3) == 0) acc0 |= v;
        else if ((j & 3) == 1) acc1 |= v;
        else if ((j & 3) == 2) acc2 |= v;
        else acc3 |= v;
      }
    }
    rem |= (acc0 | acc1) | (acc2 | acc3);
    if (lane == 0) kbits_s[c] = keepb;
    // seed next chunk's removed word (lanes nw and nw+32 hold identical data)
    int nw = (c + 1) & 31;
    u32 a0 = (u32)__builtin_amdgcn_readlane((int)(u32)rem, nw);
    u32 a1 = (u32)__builtin_amdgcn_readlane((int)(u32)(rem >> 32), nw);
    u32 b0 = (u32)__builtin_amdgcn_readlane((int)(u32)rem, nw + 32);
    u32 b1 = (u32)__builtin_amdgcn_readlane((int)(u32)(rem >> 32), nw + 32);
    cur = ((u64)(a0 | b0)) | (((u64)(a1 | b1)) << 32);
  }
  __syncthreads();

  // compact keep list: wave prefix-scan of per-chunk popcounts
  {
    int pc = (lane < NCHUNK) ? (int)__popcll(kbits_s[lane]) : 0;
    int inc = pc;
    for (int d = 1; d < 64; d <<= 1) {
      int n = __shfl_up(inc, d, 64);
      if (lane >= d) inc += n;
    }
    if (lane < NCHUNK) chunkoff[lane] = inc - pc;   // exclusive
    if (lane == NCHUNK - 1) Ksh = inc;
  }
  __syncthreads();
  for (int c = 0; c < NCHUNK; ++c) {
    u64 word = kbits_s[c];
    if ((word >> lane) & 1ULL) {
      int rank = (int)__popcll(word & ((1ULL << lane) - 1ULL));
      keeplist[chunkoff[c] + rank] = c * 64 + lane;
    }
  }
  __syncthreads();
  int K = Ksh;

  float* rois = out;
  float* probs = out + (size_t)BN * POST * 5;
  for (int r = lane; r < POST; r += 64) {
    float x1 = 0.f, y1 = 0.f, x2 = 0.f, y2 = 0.f, pr = 0.f;
    if (r < K) {
      int i = keeplist[r];
      float4 bb = boxes[b * RSTRIDE + i];
      x1 = bb.x; y1 = bb.y; x2 = bb.z; y2 = bb.w;
      pr = scores[b * RSTRIDE + i];
    }
    size_t ro = (size_t)(b * POST + r) * 5;
    rois[ro + 0] = (float)b;
    rois[ro + 1] = x1; rois[ro + 2] = y1; rois[ro + 3] = x2; rois[ro + 4] = y2;
    probs[b * POST + r] = pr;
  }
}

extern "C" void kernel_launch(void* const* d_in, const int* in_sizes, int n_in,
                              void* d_out, int out_size, void* d_ws, size_t ws_size,
                              hipStream_t stream) {
  const float* cls    = (const float*)d_in[0];
  const float* bbox   = (const float*)d_in[1];
  const float* iminfo = (const float*)d_in[2];
  const float* anch   = (const float*)d_in[3];
  char* ws = (char*)d_ws;
  u32* h1    = (u32*)(ws + OFF_H1);
  u32* h2    = (u32*)(ws + OFF_H2);
  u32* cstar = (u32*)(ws + OFF_CSTAR);
  u32* ccnt  = (u32*)(ws + OFF_CCNT);
  u32* thr   = (u32*)(ws + OFF_THR);
  u64* cand  = (u64*)(ws + OFF_CAND);
  float4* boxes = (float4*)(ws + OFF_BOX);
  float* scores = (float*)(ws + OFF_SCORE);
  int* valid    = (int*)(ws + OFF_VALID);
  u64* mask     = (u64*)(ws + OFF_MASK);
  u64* diag     = (u64*)(ws + OFF_DIAG);
  float* out = (float*)d_out;

  zero_kernel<<<(ZERO_WORDS + 255) / 256, 256, 0, stream>>>((u32*)ws, ZERO_WORDS);
  hist1_kernel<<<dim3(HBLK, BN), 256, 0, stream>>>(cls, h1);
  coarse_kernel<<<BN, 256, 0, stream>>>(h1, cstar);
  hist2_kernel<<<dim3(HBLK, BN), 256, 0, stream>>>(cls, cstar, h2);
  fine_kernel<<<BN, 256, 0, stream>>>(h2, cstar, thr);
  gather_kernel<<<NTOT / 256, 256, 0, stream>>>(cls, thr, ccnt, cand);
  sort_transform_kernel<<<BN, 1024, 0, stream>>>(cand, ccnt, bbox, iminfo, anch,
                                                 boxes, scores, valid);
  nms_mask_kernel<<<dim3(32, 32, BN), 64, 0, stream>>>(boxes, mask, diag);
  seq_nms_kernel<<<BN, 64, 0, stream>>>(mask, diag, valid, boxes, scores, out);
}

// Round 11
// 345.371 us; speedup vs baseline: 1.0303x; 1.0303x over previous
//
#include <hip/hip_runtime.h>
#include <hip/hip_bf16.h>
#include <math.h>

#define BN 8
#define AN 15
#define HH 100
#define WW 168
#define HW (HH*WW)           // 16800
#define NPI (AN*HW)          // 252000 scores per image
#define NTOT (BN*NPI)        // 2016000
#define PRE 2000
#define POST 1000
#define CAP 4096             // candidate buffer per image (threshold-bucket bound ~3000)
#define ROWW 32              // u64 words per NMS mask row (2000 bits -> 32 words)
#define NCHUNK 32            // ceil(PRE/64)
#define RSTRIDE 2048         // padded per-image row stride
#define EPB 4096             // elements per hist block
#define HBLK 62              // ceil(NPI/EPB)

typedef unsigned int u32;
typedef unsigned long long u64;

// ---- workspace layout (bytes) ----
// h1/h2 are now per-block rows (atomic-free, no zeroing needed):
// h1[b][blk][256] u32 -> 8*62*256*4 = 507904 each.
#define OFF_H1     0            // 507904
#define OFF_H2     507904      // 507904 -> 1015808
#define OFF_CSTAR  1015808     // 1024
#define OFF_CCNT   1016832     // 1024 (zeroed by fine_kernel)
#define OFF_THR    1017856     // 1024
#define OFF_CAND   1018880     // 262144 -> 1281024
#define OFF_BOX    1281024     // 262144 -> 1543168
#define OFF_SCORE  1543168     // 65536  -> 1608704
#define OFF_VALID  1608704     // 65536  -> 1674240
#define OFF_MASK   1674240     // 4194304 -> 5868544
#define OFF_DIAG   5868544     // 131072 -> 5999616 (~6 MB total)

__device__ __forceinline__ u32 fmono(float s) {
  u32 u = __float_as_uint(s);
  return (u & 0x80000000u) ? ~u : (u | 0x80000000u);
}
__device__ __forceinline__ float funmono(u32 m) {
  u32 u = (m & 0x80000000u) ? (m ^ 0x80000000u) : ~m;
  return __uint_as_float(u);
}
__device__ __forceinline__ float areaf(float4 bx) {
  return __fmul_rn(__fadd_rn(__fsub_rn(bx.z, bx.x), 1.0f),
                   __fadd_rn(__fsub_rn(bx.w, bx.y), 1.0f));
}

// phase-1 histogram: 256 coarse buckets (m>>24), LDS-privatized 4-way,
// atomic-free output: each block writes its own row (fully, incl. zeros)
__global__ __launch_bounds__(256) void hist1_kernel(const float* __restrict__ cls,
                                                    u32* __restrict__ h1) {
  __shared__ u32 lh[1024];   // 4 copies x 256 buckets
  int b = blockIdx.y;
  int t = threadIdx.x;
  for (int q = t; q < 1024; q += 256) lh[q] = 0u;
  __syncthreads();
  int start = blockIdx.x * EPB;
  int end = min(start + EPB, NPI);
  const float* p = cls + (size_t)b * NPI;
  u32 copy = ((u32)t & 3u) << 8;
  for (int i = start + t; i < end; i += 256) {
    u32 m = fmono(p[i]);
    atomicAdd(&lh[copy | (m >> 24)], 1u);
  }
  __syncthreads();
  u32 s = lh[t] + lh[t + 256] + lh[t + 512] + lh[t + 768];
  h1[((size_t)(b * HBLK) + blockIdx.x) * 256 + t] = s;   // unconditional
}

// pick coarse bucket c*: sum rows then suffix scan of 256 coarse counts
__global__ __launch_bounds__(256) void coarse_kernel(const u32* __restrict__ h1,
                                                     u32* __restrict__ cstar) {
  int b = blockIdx.x;
  int t = threadIdx.x;
  __shared__ u32 sfx[256];
  u32 s = 0;
  for (int blk = 0; blk < HBLK; ++blk) s += h1[((size_t)(b * HBLK) + blk) * 256 + t];
  sfx[t] = s;
  __syncthreads();
  for (int d = 1; d < 256; d <<= 1) {
    u32 add = (t + d < 256) ? sfx[t + d] : 0u;
    __syncthreads();
    sfx[t] += add;
    __syncthreads();
  }
  if (t == 0 && sfx[0] < (u32)PRE) { cstar[b * 32] = 0u; cstar[b * 32 + 1] = sfx[1]; }
  if (sfx[t] >= (u32)PRE && (t == 255 || sfx[t + 1] < (u32)PRE)) {
    cstar[b * 32] = (u32)t;
    cstar[b * 32 + 1] = (t == 255) ? 0u : sfx[t + 1];   // count strictly above c*
  }
}

// phase-2 histogram: 256 fine buckets ((m>>16)&0xFF), filtered to m>>24==c*,
// atomic-free per-block rows
__global__ __launch_bounds__(256) void hist2_kernel(const float* __restrict__ cls,
                                                    const u32* __restrict__ cstar,
                                                    u32* __restrict__ h2) {
  __shared__ u32 lh[256];
  int b = blockIdx.y;
  int t = threadIdx.x;
  lh[t] = 0u;
  __syncthreads();
  u32 cs = cstar[b * 32];
  int start = blockIdx.x * EPB;
  int end = min(start + EPB, NPI);
  const float* p = cls + (size_t)b * NPI;
  for (int i = start + t; i < end; i += 256) {
    u32 m = fmono(p[i]);
    if ((m >> 24) == cs) atomicAdd(&lh[(m >> 16) & 0xFFu], 1u);
  }
  __syncthreads();
  h2[((size_t)(b * HBLK) + blockIdx.x) * 256 + t] = lh[t];   // unconditional
}

// final 16-bit threshold: thr16 = (c*<<8) | k*; also zeroes ccnt for gather
__global__ __launch_bounds__(256) void fine_kernel(const u32* __restrict__ h2,
                                                   const u32* __restrict__ cstar,
                                                   u32* __restrict__ thr,
                                                   u32* __restrict__ ccnt) {
  int b = blockIdx.x;
  int t = threadIdx.x;
  __shared__ u32 sfx[256];
  u32 s = 0;
  for (int blk = 0; blk < HBLK; ++blk) s += h2[((size_t)(b * HBLK) + blk) * 256 + t];
  sfx[t] = s;
  __syncthreads();
  for (int d = 1; d < 256; d <<= 1) {
    u32 add = (t + d < 256) ? sfx[t + d] : 0u;
    __syncthreads();
    sfx[t] += add;
    __syncthreads();
  }
  u32 cs = cstar[b * 32], base = cstar[b * 32 + 1];
  if (t == 0 && base + sfx[0] < (u32)PRE) thr[b * 32] = (cs << 8);
  if (base + sfx[t] >= (u32)PRE && (t == 255 || base + sfx[t + 1] < (u32)PRE))
    thr[b * 32] = (cs << 8) | (u32)t;
  if (t == 32) ccnt[b * 32] = 0u;    // re-arm gather's counter each call
}

// wave-aggregated gather: one atomic per wave with >=1 candidate
__global__ void gather_kernel(const float* __restrict__ cls, const u32* __restrict__ thr,
                              u32* __restrict__ ccnt, u64* __restrict__ cand) {
  int tid = blockIdx.x * blockDim.x + threadIdx.x;   // grid exactly covers NTOT
  int b = tid / NPI;
  int r = tid - b * NPI;
  u32 m = fmono(cls[tid]);
  bool pass = (m >> 16) >= thr[b * 32];
  int lane = threadIdx.x & 63;
  int b0 = __shfl(b, 0, 64);
  bool uni = (__ballot(b != b0) == 0ULL);
  u32 pos = 0xffffffffu;
  if (uni) {
    u64 bal = __ballot(pass);
    if (bal) {
      int leader = __ffsll((long long)bal) - 1;
      u32 base = 0;
      if (lane == leader) base = atomicAdd(&ccnt[b * 32], (u32)__popcll(bal));
      base = __shfl(base, leader, 64);
      if (pass) pos = base + (u32)__popcll(bal & ((1ULL << lane) - 1ULL));
    }
  } else if (pass) {
    pos = atomicAdd(&ccnt[b * 32], 1u);
  }
  if (pass && pos < CAP) {
    int a  = r / HW;
    int hw = r - a * HW;
    u32 i  = (u32)(hw * AN + a);   // transposed flat index (h*W + w)*A + a
    cand[(size_t)b * CAP + pos] = ((u64)m << 32) | (u32)(~i);
  }
}

__global__ __launch_bounds__(1024) void sort_transform_kernel(
    const u64* __restrict__ cand, const u32* __restrict__ ccnt,
    const float* __restrict__ bbox, const float* __restrict__ iminfo,
    const float* __restrict__ anch,
    float4* __restrict__ boxes, float* __restrict__ scores, int* __restrict__ valid) {
  __shared__ u64 keys[CAP];   // 32 KB
  int b = blockIdx.x;
  int t = threadIdx.x;
  u32 cnt = ccnt[b * 32];
  if (cnt > CAP) cnt = CAP;
  for (int q = t; q < CAP; q += 1024) keys[q] = (q < (int)cnt) ? cand[(size_t)b * CAP + q] : 0ULL;
  __syncthreads();
  // bitonic sort, descending
  for (u32 k = 2; k <= CAP; k <<= 1) {
    for (u32 j = k >> 1; j > 0; j >>= 1) {
      for (int p = 0; p < CAP / 2 / 1024; ++p) {
        u32 idx = (u32)t + (u32)p * 1024u;           // 0..CAP/2-1
        u32 base = ((idx & ~(j - 1)) << 1) | (idx & (j - 1));
        u32 partner = base + j;
        bool up = ((base & k) == 0);
        u64 A = keys[base], B = keys[partner];
        bool sw = up ? (A < B) : (A > B);
        if (sw) { keys[base] = B; keys[partner] = A; }
      }
      __syncthreads();
    }
  }
  // transform the top PRE
  float im_h = iminfo[b * 3 + 0], im_w = iminfo[b * 3 + 1], im_s = iminfo[b * 3 + 2];
  float wmax = __fsub_rn(im_w, 1.0f), hmax = __fsub_rn(im_h, 1.0f);
  float msz = __fmul_rn(0.0f, im_s);
  const float BCLIP = (float)4.135166556742356;  // log(1000/16)
  for (int q = t; q < PRE; q += 1024) {
    u64 key = keys[q];
    u32 i = ~((u32)key);
    // defensive: pad keys (q >= cnt) decode to i >= NPI -> never dereference
    if (q >= (int)cnt || i >= (u32)NPI) {
      boxes[b * RSTRIDE + q] = make_float4(0.f, 0.f, 0.f, 0.f);
      scores[b * RSTRIDE + q] = 0.f;
      valid[b * RSTRIDE + q] = 0;
      continue;
    }
    float sc = funmono((u32)(key >> 32));
    int a = (int)(i % AN);
    int pp = (int)(i / AN);
    int w = pp % WW;
    int h = pp / WW;
    float sx = (float)(w * 8), sy = (float)(h * 8);
    float ax1 = __fadd_rn(anch[a * 4 + 0], sx);
    float ay1 = __fadd_rn(anch[a * 4 + 1], sy);
    float ax2 = __fadd_rn(anch[a * 4 + 2], sx);
    float ay2 = __fadd_rn(anch[a * 4 + 3], sy);
    float wsA = __fadd_rn(__fsub_rn(ax2, ax1), 1.0f);
    float hsA = __fadd_rn(__fsub_rn(ay2, ay1), 1.0f);
    float cx = __fadd_rn(ax1, __fmul_rn(0.5f, wsA));
    float cy = __fadd_rn(ay1, __fmul_rn(0.5f, hsA));
    const float* dp = bbox + ((size_t)b * (4 * AN) + 4 * a) * HW + (size_t)h * WW + w;
    float dx = dp[0], dy = dp[HW], dwv = dp[2 * HW], dhv = dp[3 * HW];
    dwv = fminf(dwv, BCLIP);
    dhv = fminf(dhv, BCLIP);
    float pcx = __fadd_rn(__fmul_rn(dx, wsA), cx);
    float pcy = __fadd_rn(__fmul_rn(dy, hsA), cy);
    float pw = __fmul_rn((float)exp((double)dwv), wsA);
    float ph = __fmul_rn((float)exp((double)dhv), hsA);
    float hpw = __fmul_rn(0.5f, pw), hph = __fmul_rn(0.5f, ph);
    float x1 = __fsub_rn(pcx, hpw);
    float y1 = __fsub_rn(pcy, hph);
    float x2 = __fsub_rn(__fadd_rn(pcx, hpw), 1.0f);
    float y2 = __fsub_rn(__fadd_rn(pcy, hph), 1.0f);
    x1 = fminf(fmaxf(x1, 0.0f), wmax);
    y1 = fminf(fmaxf(y1, 0.0f), hmax);
    x2 = fminf(fmaxf(x2, 0.0f), wmax);
    y2 = fminf(fmaxf(y2, 0.0f), hmax);
    float ws2 = __fadd_rn(__fsub_rn(x2, x1), 1.0f);
    float hs2 = __fadd_rn(__fsub_rn(y2, y1), 1.0f);
    int v = (ws2 >= msz) && (hs2 >= msz) &&
            (__fadd_rn(x1, __fmul_rn(ws2, 0.5f)) < im_w) &&
            (__fadd_rn(y1, __fmul_rn(hs2, 0.5f)) < im_h);
    boxes[b * RSTRIDE + q] = make_float4(x1, y1, x2, y2);
    scores[b * RSTRIDE + q] = sc;
    valid[b * RSTRIDE + q] = v;
  }
}

__global__ __launch_bounds__(64) void nms_mask_kernel(const float4* __restrict__ boxes,
                                                      u64* __restrict__ mask,
                                                      u64* __restrict__ diag) {
  int jb = blockIdx.x, ib = blockIdx.y, b = blockIdx.z;
  if (jb < ib) return;   // upper triangle only (j > i needed)
  int t = threadIdx.x;
  __shared__ float4 jbox[64];
  __shared__ float jarea[64];
  int jbase = jb * 64;
  int jcount = min(64, PRE - jbase);
  if (t < jcount) {
    float4 bj = boxes[b * RSTRIDE + jbase + t];
    jbox[t] = bj;
    jarea[t] = areaf(bj);
  }
  __syncthreads();
  int i = ib * 64 + t;
  if (i >= PRE) return;
  float4 bi = boxes[b * RSTRIDE + i];
  float ai = areaf(bi);
  u64 word = 0ULL;
  for (int jj = 0; jj < jcount; ++jj) {
    int j = jbase + jj;
    if (j <= i) continue;
    float4 bj = jbox[jj];
    float iw = fmaxf(__fadd_rn(__fsub_rn(fminf(bi.z, bj.z), fmaxf(bi.x, bj.x)), 1.0f), 0.0f);
    float ih = fmaxf(__fadd_rn(__fsub_rn(fminf(bi.w, bj.w), fmaxf(bi.y, bj.y)), 1.0f), 0.0f);
    float inter = __fmul_rn(iw, ih);
    float denom = __fsub_rn(__fadd_rn(ai, jarea[jj]), inter);
    float iou = inter / denom;
    if (iou > 0.7f) word |= (1ULL << jj);
  }
  mask[((size_t)(b * RSTRIDE) + i) * ROWW + jb] = word;
  if (jb == ib) diag[(size_t)b * RSTRIDE + i] = word;   // packed diagonal word
}

// ---------------- seq NMS v8: register fold, no LDS staging ----------------
// R10 postmortem: every LDS-staged variant pays a compiler-inserted
// s_waitcnt vmcnt(0) before the fold's ds_reads (DMA-to-LDS aliases the LDS
// being read), so each chunk's fold blocked on the NEXT chunk's full 16KB
// staging. v8 removes LDS from the data path: lane L loads column (L&31) of
// rows (L>>5)*32+r directly to registers (32 coalesced global_load_dwordx2,
// all independent), the scalar diag chain runs during the load latency, and
// the fold consumes t[32] with rotating accumulators. ~95 VGPR, no spill.
__global__ __launch_bounds__(64) void seq_nms_kernel(
    const u64* __restrict__ mask, const u64* __restrict__ diag,
    const int* __restrict__ valid,
    const float4* __restrict__ boxes, const float* __restrict__ scores,
    float* __restrict__ out) {
  int b = blockIdx.x;
  int lane = threadIdx.x;
  int lw = lane & 31, hf = lane >> 5;
  __shared__ u64 vbuf[NCHUNK];
  __shared__ u64 kbits_s[NCHUNK];
  __shared__ int chunkoff[NCHUNK];
  __shared__ int keeplist[PRE];
  __shared__ int Ksh;

  // precompute per-chunk valid ballots into LDS (unrolled: static v[] index)
  {
    int v[NCHUNK];
#pragma unroll
    for (int c = 0; c < NCHUNK; ++c) {
      int q = c * 64 + lane;
      v[c] = (q < PRE) ? valid[b * RSTRIDE + q] : 0;
    }
#pragma unroll
    for (int c = 0; c < NCHUNK; ++c) {
      u64 bl = __ballot(v[c] != 0);
      if (lane == 0) vbuf[c] = bl;
    }
  }
  __syncthreads();

  const u64* base = mask + (size_t)b * RSTRIDE * ROWW;
  const u64* dg = diag + (size_t)b * RSTRIDE;

  u64 rem = 0ULL, cur = 0ULL;
  for (int c = 0; c < NCHUNK; ++c) {
    int c0 = c * 64;
    // 32 independent coalesced loads straight to registers; no dependents
    // until the fold, so they overlap the scalar chain below
    u64 t[32];
#pragma unroll
    for (int r = 0; r < 32; ++r)
      t[r] = base[(size_t)(c0 + hf * 32 + r) * ROWW + lw];
    // wave-uniform valid mask, rescalarized
    u64 vbv = vbuf[c];
    u32 vlo = (u32)__builtin_amdgcn_readfirstlane((int)(u32)vbv);
    u32 vhi = (u32)__builtin_amdgcn_readfirstlane((int)(u32)(vbv >> 32));
    u64 vb = ((u64)vhi << 32) | vlo;
    // scalar serial chain over the chunk's diagonal words (SMEM pipe)
    const u64* dgc = dg + c * 64;
    u64 cl = cur;
#pragma unroll
    for (int ii = 0; ii < 64; ++ii) {
      u64 D = dgc[ii];                     // uniform -> s_load (merged x16)
      u64 tt = ((~cl & vb) >> ii) & 1ULL;
      cl |= tt ? D : 0ULL;                 // s_cselect_b64 + s_or_b64
    }
    u64 keepb = vb & ~cl;
    // fold from registers: this half-lane's 32 keep bits, rotating accums
    u32 kb_half = (u32)(keepb >> (hf * 32));
    u64 a0 = 0ULL, a1 = 0ULL, a2 = 0ULL, a3 = 0ULL;
#pragma unroll
    for (int r = 0; r < 32; ++r) {
      u64 km = 0ULL - (u64)((kb_half >> r) & 1u);
      u64 v = t[r] & km;
      if ((r & 3) == 0) a0 |= v;
      else if ((r & 3) == 1) a1 |= v;
      else if ((r & 3) == 2) a2 |= v;
      else a3 |= v;
    }
    rem |= (a0 | a1) | (a2 | a3);
    if (lane == 0) kbits_s[c] = keepb;
    // seed next chunk's removed word (halves combined via readlanes)
    int nw = (c + 1) & 31;
    u32 s0 = (u32)__builtin_amdgcn_readlane((int)(u32)rem, nw);
    u32 s1 = (u32)__builtin_amdgcn_readlane((int)(u32)(rem >> 32), nw);
    u32 s2 = (u32)__builtin_amdgcn_readlane((int)(u32)rem, nw + 32);
    u32 s3 = (u32)__builtin_amdgcn_readlane((int)(u32)(rem >> 32), nw + 32);
    cur = ((u64)(s0 | s2)) | (((u64)(s1 | s3)) << 32);
  }
  __syncthreads();

  // compact keep list: wave prefix-scan of per-chunk popcounts
  {
    int pc = (lane < NCHUNK) ? (int)__popcll(kbits_s[lane]) : 0;
    int inc = pc;
    for (int d = 1; d < 64; d <<= 1) {
      int n = __shfl_up(inc, d, 64);
      if (lane >= d) inc += n;
    }
    if (lane < NCHUNK) chunkoff[lane] = inc - pc;   // exclusive
    if (lane == NCHUNK - 1) Ksh = inc;
  }
  __syncthreads();
  for (int c = 0; c < NCHUNK; ++c) {
    u64 word = kbits_s[c];
    if ((word >> lane) & 1ULL) {
      int rank = (int)__popcll(word & ((1ULL << lane) - 1ULL));
      keeplist[chunkoff[c] + rank] = c * 64 + lane;
    }
  }
  __syncthreads();
  int K = Ksh;

  float* rois = out;
  float* probs = out + (size_t)BN * POST * 5;
  for (int r = lane; r < POST; r += 64) {
    float x1 = 0.f, y1 = 0.f, x2 = 0.f, y2 = 0.f, pr = 0.f;
    if (r < K) {
      int i = keeplist[r];
      float4 bb = boxes[b * RSTRIDE + i];
      x1 = bb.x; y1 = bb.y; x2 = bb.z; y2 = bb.w;
      pr = scores[b * RSTRIDE + i];
    }
    size_t ro = (size_t)(b * POST + r) * 5;
    rois[ro + 0] = (float)b;
    rois[ro + 1] = x1; rois[ro + 2] = y1; rois[ro + 3] = x2; rois[ro + 4] = y2;
    probs[b * POST + r] = pr;
  }
}

extern "C" void kernel_launch(void* const* d_in, const int* in_sizes, int n_in,
                              void* d_out, int out_size, void* d_ws, size_t ws_size,
                              hipStream_t stream) {
  const float* cls    = (const float*)d_in[0];
  const float* bbox   = (const float*)d_in[1];
  const float* iminfo = (const float*)d_in[2];
  const float* anch   = (const float*)d_in[3];
  char* ws = (char*)d_ws;
  u32* h1    = (u32*)(ws + OFF_H1);
  u32* h2    = (u32*)(ws + OFF_H2);
  u32* cstar = (u32*)(ws + OFF_CSTAR);
  u32* ccnt  = (u32*)(ws + OFF_CCNT);
  u32* thr   = (u32*)(ws + OFF_THR);
  u64* cand  = (u64*)(ws + OFF_CAND);
  float4* boxes = (float4*)(ws + OFF_BOX);
  float* scores = (float*)(ws + OFF_SCORE);
  int* valid    = (int*)(ws + OFF_VALID);
  u64* mask     = (u64*)(ws + OFF_MASK);
  u64* diag     = (u64*)(ws + OFF_DIAG);
  float* out = (float*)d_out;

  hist1_kernel<<<dim3(HBLK, BN), 256, 0, stream>>>(cls, h1);
  coarse_kernel<<<BN, 256, 0, stream>>>(h1, cstar);
  hist2_kernel<<<dim3(HBLK, BN), 256, 0, stream>>>(cls, cstar, h2);
  fine_kernel<<<BN, 256, 0, stream>>>(h2, cstar, thr, ccnt);
  gather_kernel<<<NTOT / 256, 256, 0, stream>>>(cls, thr, ccnt, cand);
  sort_transform_kernel<<<BN, 1024, 0, stream>>>(cand, ccnt, bbox, iminfo, anch,
                                                 boxes, scores, valid);
  nms_mask_kernel<<<dim3(32, 32, BN), 64, 0, stream>>>(boxes, mask, diag);
  seq_nms_kernel<<<BN, 64, 0, stream>>>(mask, diag, valid, boxes, scores, out);
}

// Round 12
// 343.395 us; speedup vs baseline: 1.0362x; 1.0058x over previous
//
#include <hip/hip_runtime.h>
#include <hip/hip_bf16.h>
#include <math.h>

#define BN 8
#define AN 15
#define HH 100
#define WW 168
#define HW (HH*WW)           // 16800
#define NPI (AN*HW)          // 252000 scores per image
#define NTOT (BN*NPI)        // 2016000
#define PRE 2000
#define POST 1000
#define CAP 4096             // candidate buffer per image (threshold-bucket bound ~3000)
#define ROWW 32              // u64 words per NMS mask row (2000 bits -> 32 words)
#define NCHUNK 32            // ceil(PRE/64)
#define RSTRIDE 2048         // padded per-image row stride
#define EPB 4096             // elements per hist block
#define HBLK 62              // ceil(NPI/EPB)

typedef unsigned int u32;
typedef unsigned long long u64;

// ---- workspace layout (bytes) ----
#define OFF_H1     0            // 507904
#define OFF_H2     507904      // 507904 -> 1015808
#define OFF_CSTAR  1015808     // 1024
#define OFF_CCNT   1016832     // 1024 (zeroed by fine_kernel)
#define OFF_THR    1017856     // 1024
#define OFF_CAND   1018880     // 262144 -> 1281024
#define OFF_BOX    1281024     // 262144 -> 1543168
#define OFF_SCORE  1543168     // 65536  -> 1608704
#define OFF_VALID  1608704     // 65536  -> 1674240
#define OFF_MASK   1674240     // 4194304 -> 5868544
#define OFF_DIAG   5868544     // 131072 -> 5999616 (~6 MB total)

__device__ __forceinline__ u32 fmono(float s) {
  u32 u = __float_as_uint(s);
  return (u & 0x80000000u) ? ~u : (u | 0x80000000u);
}
__device__ __forceinline__ float funmono(u32 m) {
  u32 u = (m & 0x80000000u) ? (m ^ 0x80000000u) : ~m;
  return __uint_as_float(u);
}
__device__ __forceinline__ float areaf(float4 bx) {
  return __fmul_rn(__fadd_rn(__fsub_rn(bx.z, bx.x), 1.0f),
                   __fadd_rn(__fsub_rn(bx.w, bx.y), 1.0f));
}

// phase-1 histogram: 256 coarse buckets (m>>24), LDS-privatized 4-way,
// atomic-free output: each block writes its own row (fully, incl. zeros)
__global__ __launch_bounds__(256) void hist1_kernel(const float* __restrict__ cls,
                                                    u32* __restrict__ h1) {
  __shared__ u32 lh[1024];   // 4 copies x 256 buckets
  int b = blockIdx.y;
  int t = threadIdx.x;
  for (int q = t; q < 1024; q += 256) lh[q] = 0u;
  __syncthreads();
  int start = blockIdx.x * EPB;
  int end = min(start + EPB, NPI);
  const float* p = cls + (size_t)b * NPI;
  u32 copy = ((u32)t & 3u) << 8;
  for (int i = start + t; i < end; i += 256) {
    u32 m = fmono(p[i]);
    atomicAdd(&lh[copy | (m >> 24)], 1u);
  }
  __syncthreads();
  u32 s = lh[t] + lh[t + 256] + lh[t + 512] + lh[t + 768];
  h1[((size_t)(b * HBLK) + blockIdx.x) * 256 + t] = s;   // unconditional
}

// pick coarse bucket c*: sum rows then suffix scan of 256 coarse counts
__global__ __launch_bounds__(256) void coarse_kernel(const u32* __restrict__ h1,
                                                     u32* __restrict__ cstar) {
  int b = blockIdx.x;
  int t = threadIdx.x;
  __shared__ u32 sfx[256];
  u32 s = 0;
  for (int blk = 0; blk < HBLK; ++blk) s += h1[((size_t)(b * HBLK) + blk) * 256 + t];
  sfx[t] = s;
  __syncthreads();
  for (int d = 1; d < 256; d <<= 1) {
    u32 add = (t + d < 256) ? sfx[t + d] : 0u;
    __syncthreads();
    sfx[t] += add;
    __syncthreads();
  }
  if (t == 0 && sfx[0] < (u32)PRE) { cstar[b * 32] = 0u; cstar[b * 32 + 1] = sfx[1]; }
  if (sfx[t] >= (u32)PRE && (t == 255 || sfx[t + 1] < (u32)PRE)) {
    cstar[b * 32] = (u32)t;
    cstar[b * 32 + 1] = (t == 255) ? 0u : sfx[t + 1];   // count strictly above c*
  }
}

// phase-2 histogram: 256 fine buckets ((m>>16)&0xFF), filtered to m>>24==c*,
// atomic-free per-block rows
__global__ __launch_bounds__(256) void hist2_kernel(const float* __restrict__ cls,
                                                    const u32* __restrict__ cstar,
                                                    u32* __restrict__ h2) {
  __shared__ u32 lh[256];
  int b = blockIdx.y;
  int t = threadIdx.x;
  lh[t] = 0u;
  __syncthreads();
  u32 cs = cstar[b * 32];
  int start = blockIdx.x * EPB;
  int end = min(start + EPB, NPI);
  const float* p = cls + (size_t)b * NPI;
  for (int i = start + t; i < end; i += 256) {
    u32 m = fmono(p[i]);
    if ((m >> 24) == cs) atomicAdd(&lh[(m >> 16) & 0xFFu], 1u);
  }
  __syncthreads();
  h2[((size_t)(b * HBLK) + blockIdx.x) * 256 + t] = lh[t];   // unconditional
}

// final 16-bit threshold: thr16 = (c*<<8) | k*; also zeroes ccnt for gather
__global__ __launch_bounds__(256) void fine_kernel(const u32* __restrict__ h2,
                                                   const u32* __restrict__ cstar,
                                                   u32* __restrict__ thr,
                                                   u32* __restrict__ ccnt) {
  int b = blockIdx.x;
  int t = threadIdx.x;
  __shared__ u32 sfx[256];
  u32 s = 0;
  for (int blk = 0; blk < HBLK; ++blk) s += h2[((size_t)(b * HBLK) + blk) * 256 + t];
  sfx[t] = s;
  __syncthreads();
  for (int d = 1; d < 256; d <<= 1) {
    u32 add = (t + d < 256) ? sfx[t + d] : 0u;
    __syncthreads();
    sfx[t] += add;
    __syncthreads();
  }
  u32 cs = cstar[b * 32], base = cstar[b * 32 + 1];
  if (t == 0 && base + sfx[0] < (u32)PRE) thr[b * 32] = (cs << 8);
  if (base + sfx[t] >= (u32)PRE && (t == 255 || base + sfx[t + 1] < (u32)PRE))
    thr[b * 32] = (cs << 8) | (u32)t;
  if (t == 32) ccnt[b * 32] = 0u;    // re-arm gather's counter each call
}

// wave-aggregated gather: one atomic per wave with >=1 candidate
__global__ void gather_kernel(const float* __restrict__ cls, const u32* __restrict__ thr,
                              u32* __restrict__ ccnt, u64* __restrict__ cand) {
  int tid = blockIdx.x * blockDim.x + threadIdx.x;   // grid exactly covers NTOT
  int b = tid / NPI;
  int r = tid - b * NPI;
  u32 m = fmono(cls[tid]);
  bool pass = (m >> 16) >= thr[b * 32];
  int lane = threadIdx.x & 63;
  int b0 = __shfl(b, 0, 64);
  bool uni = (__ballot(b != b0) == 0ULL);
  u32 pos = 0xffffffffu;
  if (uni) {
    u64 bal = __ballot(pass);
    if (bal) {
      int leader = __ffsll((long long)bal) - 1;
      u32 base = 0;
      if (lane == leader) base = atomicAdd(&ccnt[b * 32], (u32)__popcll(bal));
      base = __shfl(base, leader, 64);
      if (pass) pos = base + (u32)__popcll(bal & ((1ULL << lane) - 1ULL));
    }
  } else if (pass) {
    pos = atomicAdd(&ccnt[b * 32], 1u);
  }
  if (pass && pos < CAP) {
    int a  = r / HW;
    int hw = r - a * HW;
    u32 i  = (u32)(hw * AN + a);   // transposed flat index (h*W + w)*A + a
    cand[(size_t)b * CAP + pos] = ((u64)m << 32) | (u32)(~i);
  }
}

__global__ __launch_bounds__(1024) void sort_transform_kernel(
    const u64* __restrict__ cand, const u32* __restrict__ ccnt,
    const float* __restrict__ bbox, const float* __restrict__ iminfo,
    const float* __restrict__ anch,
    float4* __restrict__ boxes, float* __restrict__ scores, int* __restrict__ valid) {
  __shared__ u64 keys[CAP];   // 32 KB
  int b = blockIdx.x;
  int t = threadIdx.x;
  u32 cnt = ccnt[b * 32];
  if (cnt > CAP) cnt = CAP;
  for (int q = t; q < CAP; q += 1024) keys[q] = (q < (int)cnt) ? cand[(size_t)b * CAP + q] : 0ULL;
  __syncthreads();
  // bitonic sort, descending
  for (u32 k = 2; k <= CAP; k <<= 1) {
    for (u32 j = k >> 1; j > 0; j >>= 1) {
      for (int p = 0; p < CAP / 2 / 1024; ++p) {
        u32 idx = (u32)t + (u32)p * 1024u;           // 0..CAP/2-1
        u32 base = ((idx & ~(j - 1)) << 1) | (idx & (j - 1));
        u32 partner = base + j;
        bool up = ((base & k) == 0);
        u64 A = keys[base], B = keys[partner];
        bool sw = up ? (A < B) : (A > B);
        if (sw) { keys[base] = B; keys[partner] = A; }
      }
      __syncthreads();
    }
  }
  // transform the top PRE
  float im_h = iminfo[b * 3 + 0], im_w = iminfo[b * 3 + 1], im_s = iminfo[b * 3 + 2];
  float wmax = __fsub_rn(im_w, 1.0f), hmax = __fsub_rn(im_h, 1.0f);
  float msz = __fmul_rn(0.0f, im_s);
  const float BCLIP = (float)4.135166556742356;  // log(1000/16)
  for (int q = t; q < PRE; q += 1024) {
    u64 key = keys[q];
    u32 i = ~((u32)key);
    // defensive: pad keys (q >= cnt) decode to i >= NPI -> never dereference
    if (q >= (int)cnt || i >= (u32)NPI) {
      boxes[b * RSTRIDE + q] = make_float4(0.f, 0.f, 0.f, 0.f);
      scores[b * RSTRIDE + q] = 0.f;
      valid[b * RSTRIDE + q] = 0;
      continue;
    }
    float sc = funmono((u32)(key >> 32));
    int a = (int)(i % AN);
    int pp = (int)(i / AN);
    int w = pp % WW;
    int h = pp / WW;
    float sx = (float)(w * 8), sy = (float)(h * 8);
    float ax1 = __fadd_rn(anch[a * 4 + 0], sx);
    float ay1 = __fadd_rn(anch[a * 4 + 1], sy);
    float ax2 = __fadd_rn(anch[a * 4 + 2], sx);
    float ay2 = __fadd_rn(anch[a * 4 + 3], sy);
    float wsA = __fadd_rn(__fsub_rn(ax2, ax1), 1.0f);
    float hsA = __fadd_rn(__fsub_rn(ay2, ay1), 1.0f);
    float cx = __fadd_rn(ax1, __fmul_rn(0.5f, wsA));
    float cy = __fadd_rn(ay1, __fmul_rn(0.5f, hsA));
    const float* dp = bbox + ((size_t)b * (4 * AN) + 4 * a) * HW + (size_t)h * WW + w;
    float dx = dp[0], dy = dp[HW], dwv = dp[2 * HW], dhv = dp[3 * HW];
    dwv = fminf(dwv, BCLIP);
    dhv = fminf(dhv, BCLIP);
    float pcx = __fadd_rn(__fmul_rn(dx, wsA), cx);
    float pcy = __fadd_rn(__fmul_rn(dy, hsA), cy);
    float pw = __fmul_rn((float)exp((double)dwv), wsA);
    float ph = __fmul_rn((float)exp((double)dhv), hsA);
    float hpw = __fmul_rn(0.5f, pw), hph = __fmul_rn(0.5f, ph);
    float x1 = __fsub_rn(pcx, hpw);
    float y1 = __fsub_rn(pcy, hph);
    float x2 = __fsub_rn(__fadd_rn(pcx, hpw), 1.0f);
    float y2 = __fsub_rn(__fadd_rn(pcy, hph), 1.0f);
    x1 = fminf(fmaxf(x1, 0.0f), wmax);
    y1 = fminf(fmaxf(y1, 0.0f), hmax);
    x2 = fminf(fmaxf(x2, 0.0f), wmax);
    y2 = fminf(fmaxf(y2, 0.0f), hmax);
    float ws2 = __fadd_rn(__fsub_rn(x2, x1), 1.0f);
    float hs2 = __fadd_rn(__fsub_rn(y2, y1), 1.0f);
    int v = (ws2 >= msz) && (hs2 >= msz) &&
            (__fadd_rn(x1, __fmul_rn(ws2, 0.5f)) < im_w) &&
            (__fadd_rn(y1, __fmul_rn(hs2, 0.5f)) < im_h);
    boxes[b * RSTRIDE + q] = make_float4(x1, y1, x2, y2);
    scores[b * RSTRIDE + q] = sc;
    valid[b * RSTRIDE + q] = v;
  }
}

__global__ __launch_bounds__(64) void nms_mask_kernel(const float4* __restrict__ boxes,
                                                      u64* __restrict__ mask,
                                                      u64* __restrict__ diag) {
  int jb = blockIdx.x, ib = blockIdx.y, b = blockIdx.z;
  if (jb < ib) return;   // upper triangle only (j > i needed)
  int t = threadIdx.x;
  __shared__ float4 jbox[64];
  __shared__ float jarea[64];
  int jbase = jb * 64;
  int jcount = min(64, PRE - jbase);
  if (t < jcount) {
    float4 bj = boxes[b * RSTRIDE + jbase + t];
    jbox[t] = bj;
    jarea[t] = areaf(bj);
  }
  __syncthreads();
  int i = ib * 64 + t;
  if (i >= PRE) return;
  float4 bi = boxes[b * RSTRIDE + i];
  float ai = areaf(bi);
  u64 word = 0ULL;
  for (int jj = 0; jj < jcount; ++jj) {
    int j = jbase + jj;
    if (j <= i) continue;
    float4 bj = jbox[jj];
    float iw = fmaxf(__fadd_rn(__fsub_rn(fminf(bi.z, bj.z), fmaxf(bi.x, bj.x)), 1.0f), 0.0f);
    float ih = fmaxf(__fadd_rn(__fsub_rn(fminf(bi.w, bj.w), fmaxf(bi.y, bj.y)), 1.0f), 0.0f);
    float inter = __fmul_rn(iw, ih);
    float denom = __fsub_rn(__fadd_rn(ai, jarea[jj]), inter);
    float iou = inter / denom;
    if (iou > 0.7f) word |= (1ULL << jj);
  }
  mask[((size_t)(b * RSTRIDE) + i) * ROWW + jb] = word;
  if (jb == ib) diag[(size_t)b * RSTRIDE + i] = word;   // packed diagonal word
}

// ---------------- seq NMS v9: 8-wave fold, barrier-fenced prefetch -------
// R11 postmortem: in a barrier-free single-wave loop the scheduler sinks
// loads to uses (VGPR_Count=48 despite t[32]) -> 32 serialized ~200cyc loads
// per chunk. v9 uses 8 waves/image: each wave loads only 4 coalesced 512B
// rows per chunk (issued BEFORE the barrier -- barriers double as scheduler
// fences), wave 0 runs the verified scalar diag chain while other waves'
// loads drain in parallel, then all waves fold 1/8th of the tile and the 16
// (wave,half) lanes holding word c+1 publish partial rem to LDS slots.
__global__ __launch_bounds__(512) void seq_nms_kernel(
    const u64* __restrict__ mask, const u64* __restrict__ diag,
    const int* __restrict__ valid,
    const float4* __restrict__ boxes, const float* __restrict__ scores,
    float* __restrict__ out) {
  int b = blockIdx.x;
  int tid = threadIdx.x;
  int wid = tid >> 6, lane = tid & 63, lw = lane & 31, hf = lane >> 5;
  __shared__ u64 partial[16];
  __shared__ u64 keepbLDS;
  __shared__ u64 vbufLDS[NCHUNK];
  __shared__ u64 kbits_s[NCHUNK];
  __shared__ int chunkoff[NCHUNK];
  __shared__ int keeplist[PRE];
  __shared__ int Ksh;

  if (tid < 16) partial[tid] = 0ULL;
  if (wid == 0) {
    for (int c = 0; c < NCHUNK; ++c) {
      int q = c * 64 + lane;
      int v = (q < PRE) ? valid[b * RSTRIDE + q] : 0;
      u64 bl = __ballot(v != 0);
      if (lane == 0) vbufLDS[c] = bl;
    }
  }
  __syncthreads();

  const u64* base = mask + (size_t)b * RSTRIDE * ROWW;
  const u64* dg = diag + (size_t)b * RSTRIDE;

  u64 rem = 0ULL;
  int rb0 = wid * 8 + hf;    // this lane's rows: rb0, rb0+2, rb0+4, rb0+6
  for (int c = 0; c < NCHUNK; ++c) {
    int c0 = c * 64;
    // 4 coalesced loads (512B each), independent of keepb; issued pre-barrier
    u64 t0 = base[(size_t)(c0 + rb0 + 0) * ROWW + lw];
    u64 t1 = base[(size_t)(c0 + rb0 + 2) * ROWW + lw];
    u64 t2 = base[(size_t)(c0 + rb0 + 4) * ROWW + lw];
    u64 t3 = base[(size_t)(c0 + rb0 + 6) * ROWW + lw];
    if (wid == 0) {
      // cur = OR of 16 partial slots (uniform VALU), then scalarize
      u64 cv = partial[0];
#pragma unroll
      for (int s = 1; s < 16; ++s) cv |= partial[s];
      u32 clo = (u32)__builtin_amdgcn_readfirstlane((int)(u32)cv);
      u32 chi = (u32)__builtin_amdgcn_readfirstlane((int)(u32)(cv >> 32));
      u64 cl = ((u64)chi << 32) | clo;
      u64 vbv = vbufLDS[c];
      u32 vlo = (u32)__builtin_amdgcn_readfirstlane((int)(u32)vbv);
      u32 vhi = (u32)__builtin_amdgcn_readfirstlane((int)(u32)(vbv >> 32));
      u64 vb = ((u64)vhi << 32) | vlo;
      const u64* dgc = dg + c * 64;
#pragma unroll
      for (int ii = 0; ii < 64; ++ii) {
        u64 D = dgc[ii];                   // uniform -> s_load (merged)
        u64 tt = ((~cl & vb) >> ii) & 1ULL;
        cl |= tt ? D : 0ULL;               // s_cselect_b64 + s_or_b64
      }
      u64 keepb = vb & ~cl;
      if (lane == 0) { keepbLDS = keepb; kbits_s[c] = keepb; }
    }
    __syncthreads();
    u64 keepb = keepbLDS;                  // broadcast
    rem |= t0 & (0ULL - ((keepb >> (rb0 + 0)) & 1ULL));
    rem |= t1 & (0ULL - ((keepb >> (rb0 + 2)) & 1ULL));
    rem |= t2 & (0ULL - ((keepb >> (rb0 + 4)) & 1ULL));
    rem |= t3 & (0ULL - ((keepb >> (rb0 + 6)) & 1ULL));
    int nw = (c + 1) & 31;
    if (lw == nw) partial[wid * 2 + hf] = rem;   // cumulative, 16 writers
    __syncthreads();
  }

  // compact keep list: wave-0 prefix-scan of per-chunk popcounts
  if (wid == 0) {
    int pc = (lane < NCHUNK) ? (int)__popcll(kbits_s[lane]) : 0;
    int inc = pc;
    for (int d = 1; d < 64; d <<= 1) {
      int n = __shfl_up(inc, d, 64);
      if (lane >= d) inc += n;
    }
    if (lane < NCHUNK) chunkoff[lane] = inc - pc;   // exclusive
    if (lane == NCHUNK - 1) Ksh = inc;
  }
  __syncthreads();
  // scatter: 4 chunks per wave
  for (int c = wid * 4; c < wid * 4 + 4; ++c) {
    u64 word = kbits_s[c];
    if ((word >> lane) & 1ULL) {
      int rank = (int)__popcll(word & ((1ULL << lane) - 1ULL));
      keeplist[chunkoff[c] + rank] = c * 64 + lane;
    }
  }
  __syncthreads();
  int K = Ksh;

  float* rois = out;
  float* probs = out + (size_t)BN * POST * 5;
  for (int r = tid; r < POST; r += 512) {
    float x1 = 0.f, y1 = 0.f, x2 = 0.f, y2 = 0.f, pr = 0.f;
    if (r < K) {
      int i = keeplist[r];
      float4 bb = boxes[b * RSTRIDE + i];
      x1 = bb.x; y1 = bb.y; x2 = bb.z; y2 = bb.w;
      pr = scores[b * RSTRIDE + i];
    }
    size_t ro = (size_t)(b * POST + r) * 5;
    rois[ro + 0] = (float)b;
    rois[ro + 1] = x1; rois[ro + 2] = y1; rois[ro + 3] = x2; rois[ro + 4] = y2;
    probs[b * POST + r] = pr;
  }
}

extern "C" void kernel_launch(void* const* d_in, const int* in_sizes, int n_in,
                              void* d_out, int out_size, void* d_ws, size_t ws_size,
                              hipStream_t stream) {
  const float* cls    = (const float*)d_in[0];
  const float* bbox   = (const float*)d_in[1];
  const float* iminfo = (const float*)d_in[2];
  const float* anch   = (const float*)d_in[3];
  char* ws = (char*)d_ws;
  u32* h1    = (u32*)(ws + OFF_H1);
  u32* h2    = (u32*)(ws + OFF_H2);
  u32* cstar = (u32*)(ws + OFF_CSTAR);
  u32* ccnt  = (u32*)(ws + OFF_CCNT);
  u32* thr   = (u32*)(ws + OFF_THR);
  u64* cand  = (u64*)(ws + OFF_CAND);
  float4* boxes = (float4*)(ws + OFF_BOX);
  float* scores = (float*)(ws + OFF_SCORE);
  int* valid    = (int*)(ws + OFF_VALID);
  u64* mask     = (u64*)(ws + OFF_MASK);
  u64* diag     = (u64*)(ws + OFF_DIAG);
  float* out = (float*)d_out;

  hist1_kernel<<<dim3(HBLK, BN), 256, 0, stream>>>(cls, h1);
  coarse_kernel<<<BN, 256, 0, stream>>>(h1, cstar);
  hist2_kernel<<<dim3(HBLK, BN), 256, 0, stream>>>(cls, cstar, h2);
  fine_kernel<<<BN, 256, 0, stream>>>(h2, cstar, thr, ccnt);
  gather_kernel<<<NTOT / 256, 256, 0, stream>>>(cls, thr, ccnt, cand);
  sort_transform_kernel<<<BN, 1024, 0, stream>>>(cand, ccnt, bbox, iminfo, anch,
                                                 boxes, scores, valid);
  nms_mask_kernel<<<dim3(32, 32, BN), 64, 0, stream>>>(boxes, mask, diag);
  seq_nms_kernel<<<BN, 512, 0, stream>>>(mask, diag, valid, boxes, scores, out);
}

// Round 13
// 319.170 us; speedup vs baseline: 1.1149x; 1.0759x over previous
//
#include <hip/hip_runtime.h>
#include <hip/hip_bf16.h>
#include <math.h>

#define BN 8
#define AN 15
#define HH 100
#define WW 168
#define HW (HH*WW)           // 16800
#define NPI (AN*HW)          // 252000 scores per image
#define NTOT (BN*NPI)        // 2016000
#define PRE 2000
#define POST 1000
#define CAP 4096             // candidate buffer per image (threshold-bucket bound ~3000)
#define ROWW 32              // u64 words per NMS mask row (2000 bits -> 32 words)
#define NCHUNK 32            // ceil(PRE/64)
#define RSTRIDE 2048         // padded per-image row stride
#define EPB 4096             // elements per hist block
#define HBLK 62              // ceil(NPI/EPB)

typedef unsigned int u32;
typedef unsigned long long u64;

// ---- workspace layout (bytes) ----
#define OFF_H1     0            // 507904
#define OFF_H2     507904      // 507904 -> 1015808
#define OFF_CSTAR  1015808     // 1024
#define OFF_CCNT   1016832     // 1024 (zeroed by fine_kernel)
#define OFF_THR    1017856     // 1024
#define OFF_CAND   1018880     // 262144 -> 1281024
#define OFF_BOX    1281024     // 262144 -> 1543168
#define OFF_SCORE  1543168     // 65536  -> 1608704
#define OFF_VALID  1608704     // 65536  -> 1674240
#define OFF_MASK   1674240     // 4194304 -> 5868544
#define OFF_DIAG   5868544     // 131072 -> 5999616 (~6 MB total)

__device__ __forceinline__ u32 fmono(float s) {
  u32 u = __float_as_uint(s);
  return (u & 0x80000000u) ? ~u : (u | 0x80000000u);
}
__device__ __forceinline__ float funmono(u32 m) {
  u32 u = (m & 0x80000000u) ? (m ^ 0x80000000u) : ~m;
  return __uint_as_float(u);
}
__device__ __forceinline__ float areaf(float4 bx) {
  return __fmul_rn(__fadd_rn(__fsub_rn(bx.z, bx.x), 1.0f),
                   __fadd_rn(__fsub_rn(bx.w, bx.y), 1.0f));
}

// phase-1 histogram: 256 coarse buckets (m>>24), LDS-privatized 4-way,
// atomic-free output: each block writes its own row (fully, incl. zeros)
__global__ __launch_bounds__(256) void hist1_kernel(const float* __restrict__ cls,
                                                    u32* __restrict__ h1) {
  __shared__ u32 lh[1024];   // 4 copies x 256 buckets
  int b = blockIdx.y;
  int t = threadIdx.x;
  for (int q = t; q < 1024; q += 256) lh[q] = 0u;
  __syncthreads();
  int start = blockIdx.x * EPB;
  int end = min(start + EPB, NPI);
  const float* p = cls + (size_t)b * NPI;
  u32 copy = ((u32)t & 3u) << 8;
  for (int i = start + t; i < end; i += 256) {
    u32 m = fmono(p[i]);
    atomicAdd(&lh[copy | (m >> 24)], 1u);
  }
  __syncthreads();
  u32 s = lh[t] + lh[t + 256] + lh[t + 512] + lh[t + 768];
  h1[((size_t)(b * HBLK) + blockIdx.x) * 256 + t] = s;   // unconditional
}

// pick coarse bucket c*: sum rows then suffix scan of 256 coarse counts
__global__ __launch_bounds__(256) void coarse_kernel(const u32* __restrict__ h1,
                                                     u32* __restrict__ cstar) {
  int b = blockIdx.x;
  int t = threadIdx.x;
  __shared__ u32 sfx[256];
  u32 s = 0;
  for (int blk = 0; blk < HBLK; ++blk) s += h1[((size_t)(b * HBLK) + blk) * 256 + t];
  sfx[t] = s;
  __syncthreads();
  for (int d = 1; d < 256; d <<= 1) {
    u32 add = (t + d < 256) ? sfx[t + d] : 0u;
    __syncthreads();
    sfx[t] += add;
    __syncthreads();
  }
  if (t == 0 && sfx[0] < (u32)PRE) { cstar[b * 32] = 0u; cstar[b * 32 + 1] = sfx[1]; }
  if (sfx[t] >= (u32)PRE && (t == 255 || sfx[t + 1] < (u32)PRE)) {
    cstar[b * 32] = (u32)t;
    cstar[b * 32 + 1] = (t == 255) ? 0u : sfx[t + 1];   // count strictly above c*
  }
}

// phase-2 histogram: 256 fine buckets ((m>>16)&0xFF), filtered to m>>24==c*,
// atomic-free per-block rows
__global__ __launch_bounds__(256) void hist2_kernel(const float* __restrict__ cls,
                                                    const u32* __restrict__ cstar,
                                                    u32* __restrict__ h2) {
  __shared__ u32 lh[256];
  int b = blockIdx.y;
  int t = threadIdx.x;
  lh[t] = 0u;
  __syncthreads();
  u32 cs = cstar[b * 32];
  int start = blockIdx.x * EPB;
  int end = min(start + EPB, NPI);
  const float* p = cls + (size_t)b * NPI;
  for (int i = start + t; i < end; i += 256) {
    u32 m = fmono(p[i]);
    if ((m >> 24) == cs) atomicAdd(&lh[(m >> 16) & 0xFFu], 1u);
  }
  __syncthreads();
  h2[((size_t)(b * HBLK) + blockIdx.x) * 256 + t] = lh[t];   // unconditional
}

// final 16-bit threshold: thr16 = (c*<<8) | k*; also zeroes ccnt for gather
__global__ __launch_bounds__(256) void fine_kernel(const u32* __restrict__ h2,
                                                   const u32* __restrict__ cstar,
                                                   u32* __restrict__ thr,
                                                   u32* __restrict__ ccnt) {
  int b = blockIdx.x;
  int t = threadIdx.x;
  __shared__ u32 sfx[256];
  u32 s = 0;
  for (int blk = 0; blk < HBLK; ++blk) s += h2[((size_t)(b * HBLK) + blk) * 256 + t];
  sfx[t] = s;
  __syncthreads();
  for (int d = 1; d < 256; d <<= 1) {
    u32 add = (t + d < 256) ? sfx[t + d] : 0u;
    __syncthreads();
    sfx[t] += add;
    __syncthreads();
  }
  u32 cs = cstar[b * 32], base = cstar[b * 32 + 1];
  if (t == 0 && base + sfx[0] < (u32)PRE) thr[b * 32] = (cs << 8);
  if (base + sfx[t] >= (u32)PRE && (t == 255 || base + sfx[t + 1] < (u32)PRE))
    thr[b * 32] = (cs << 8) | (u32)t;
  if (t == 32) ccnt[b * 32] = 0u;    // re-arm gather's counter each call
}

// wave-aggregated gather: one atomic per wave with >=1 candidate
__global__ void gather_kernel(const float* __restrict__ cls, const u32* __restrict__ thr,
                              u32* __restrict__ ccnt, u64* __restrict__ cand) {
  int tid = blockIdx.x * blockDim.x + threadIdx.x;   // grid exactly covers NTOT
  int b = tid / NPI;
  int r = tid - b * NPI;
  u32 m = fmono(cls[tid]);
  bool pass = (m >> 16) >= thr[b * 32];
  int lane = threadIdx.x & 63;
  int b0 = __shfl(b, 0, 64);
  bool uni = (__ballot(b != b0) == 0ULL);
  u32 pos = 0xffffffffu;
  if (uni) {
    u64 bal = __ballot(pass);
    if (bal) {
      int leader = __ffsll((long long)bal) - 1;
      u32 base = 0;
      if (lane == leader) base = atomicAdd(&ccnt[b * 32], (u32)__popcll(bal));
      base = __shfl(base, leader, 64);
      if (pass) pos = base + (u32)__popcll(bal & ((1ULL << lane) - 1ULL));
    }
  } else if (pass) {
    pos = atomicAdd(&ccnt[b * 32], 1u);
  }
  if (pass && pos < CAP) {
    int a  = r / HW;
    int hw = r - a * HW;
    u32 i  = (u32)(hw * AN + a);   // transposed flat index (h*W + w)*A + a
    cand[(size_t)b * CAP + pos] = ((u64)m << 32) | (u32)(~i);
  }
}

__global__ __launch_bounds__(1024) void sort_transform_kernel(
    const u64* __restrict__ cand, const u32* __restrict__ ccnt,
    const float* __restrict__ bbox, const float* __restrict__ iminfo,
    const float* __restrict__ anch,
    float4* __restrict__ boxes, float* __restrict__ scores, int* __restrict__ valid) {
  __shared__ u64 keys[CAP];   // 32 KB
  int b = blockIdx.x;
  int t = threadIdx.x;
  u32 cnt = ccnt[b * 32];
  if (cnt > CAP) cnt = CAP;
  for (int q = t; q < CAP; q += 1024) keys[q] = (q < (int)cnt) ? cand[(size_t)b * CAP + q] : 0ULL;
  __syncthreads();
  // bitonic sort, descending
  for (u32 k = 2; k <= CAP; k <<= 1) {
    for (u32 j = k >> 1; j > 0; j >>= 1) {
      for (int p = 0; p < CAP / 2 / 1024; ++p) {
        u32 idx = (u32)t + (u32)p * 1024u;           // 0..CAP/2-1
        u32 base = ((idx & ~(j - 1)) << 1) | (idx & (j - 1));
        u32 partner = base + j;
        bool up = ((base & k) == 0);
        u64 A = keys[base], B = keys[partner];
        bool sw = up ? (A < B) : (A > B);
        if (sw) { keys[base] = B; keys[partner] = A; }
      }
      __syncthreads();
    }
  }
  // transform the top PRE
  float im_h = iminfo[b * 3 + 0], im_w = iminfo[b * 3 + 1], im_s = iminfo[b * 3 + 2];
  float wmax = __fsub_rn(im_w, 1.0f), hmax = __fsub_rn(im_h, 1.0f);
  float msz = __fmul_rn(0.0f, im_s);
  const float BCLIP = (float)4.135166556742356;  // log(1000/16)
  for (int q = t; q < PRE; q += 1024) {
    u64 key = keys[q];
    u32 i = ~((u32)key);
    // defensive: pad keys (q >= cnt) decode to i >= NPI -> never dereference
    if (q >= (int)cnt || i >= (u32)NPI) {
      boxes[b * RSTRIDE + q] = make_float4(0.f, 0.f, 0.f, 0.f);
      scores[b * RSTRIDE + q] = 0.f;
      valid[b * RSTRIDE + q] = 0;
      continue;
    }
    float sc = funmono((u32)(key >> 32));
    int a = (int)(i % AN);
    int pp = (int)(i / AN);
    int w = pp % WW;
    int h = pp / WW;
    float sx = (float)(w * 8), sy = (float)(h * 8);
    float ax1 = __fadd_rn(anch[a * 4 + 0], sx);
    float ay1 = __fadd_rn(anch[a * 4 + 1], sy);
    float ax2 = __fadd_rn(anch[a * 4 + 2], sx);
    float ay2 = __fadd_rn(anch[a * 4 + 3], sy);
    float wsA = __fadd_rn(__fsub_rn(ax2, ax1), 1.0f);
    float hsA = __fadd_rn(__fsub_rn(ay2, ay1), 1.0f);
    float cx = __fadd_rn(ax1, __fmul_rn(0.5f, wsA));
    float cy = __fadd_rn(ay1, __fmul_rn(0.5f, hsA));
    const float* dp = bbox + ((size_t)b * (4 * AN) + 4 * a) * HW + (size_t)h * WW + w;
    float dx = dp[0], dy = dp[HW], dwv = dp[2 * HW], dhv = dp[3 * HW];
    dwv = fminf(dwv, BCLIP);
    dhv = fminf(dhv, BCLIP);
    float pcx = __fadd_rn(__fmul_rn(dx, wsA), cx);
    float pcy = __fadd_rn(__fmul_rn(dy, hsA), cy);
    float pw = __fmul_rn((float)exp((double)dwv), wsA);
    float ph = __fmul_rn((float)exp((double)dhv), hsA);
    float hpw = __fmul_rn(0.5f, pw), hph = __fmul_rn(0.5f, ph);
    float x1 = __fsub_rn(pcx, hpw);
    float y1 = __fsub_rn(pcy, hph);
    float x2 = __fsub_rn(__fadd_rn(pcx, hpw), 1.0f);
    float y2 = __fsub_rn(__fadd_rn(pcy, hph), 1.0f);
    x1 = fminf(fmaxf(x1, 0.0f), wmax);
    y1 = fminf(fmaxf(y1, 0.0f), hmax);
    x2 = fminf(fmaxf(x2, 0.0f), wmax);
    y2 = fminf(fmaxf(y2, 0.0f), hmax);
    float ws2 = __fadd_rn(__fsub_rn(x2, x1), 1.0f);
    float hs2 = __fadd_rn(__fsub_rn(y2, y1), 1.0f);
    int v = (ws2 >= msz) && (hs2 >= msz) &&
            (__fadd_rn(x1, __fmul_rn(ws2, 0.5f)) < im_w) &&
            (__fadd_rn(y1, __fmul_rn(hs2, 0.5f)) < im_h);
    boxes[b * RSTRIDE + q] = make_float4(x1, y1, x2, y2);
    scores[b * RSTRIDE + q] = sc;
    valid[b * RSTRIDE + q] = v;
  }
}

__global__ __launch_bounds__(64) void nms_mask_kernel(const float4* __restrict__ boxes,
                                                      u64* __restrict__ mask,
                                                      u64* __restrict__ diag) {
  int jb = blockIdx.x, ib = blockIdx.y, b = blockIdx.z;
  if (jb < ib) return;   // upper triangle only (j > i needed)
  int t = threadIdx.x;
  __shared__ float4 jbox[64];
  __shared__ float jarea[64];
  int jbase = jb * 64;
  int jcount = min(64, PRE - jbase);
  if (t < jcount) {
    float4 bj = boxes[b * RSTRIDE + jbase + t];
    jbox[t] = bj;
    jarea[t] = areaf(bj);
  }
  __syncthreads();
  int i = ib * 64 + t;
  if (i >= PRE) return;
  float4 bi = boxes[b * RSTRIDE + i];
  float ai = areaf(bi);
  u64 word = 0ULL;
  for (int jj = 0; jj < jcount; ++jj) {
    int j = jbase + jj;
    if (j <= i) continue;
    float4 bj = jbox[jj];
    float iw = fmaxf(__fadd_rn(__fsub_rn(fminf(bi.z, bj.z), fmaxf(bi.x, bj.x)), 1.0f), 0.0f);
    float ih = fmaxf(__fadd_rn(__fsub_rn(fminf(bi.w, bj.w), fmaxf(bi.y, bj.y)), 1.0f), 0.0f);
    float inter = __fmul_rn(iw, ih);
    float denom = __fsub_rn(__fadd_rn(ai, jarea[jj]), inter);
    float iou = inter / denom;
    if (iou > 0.7f) word |= (1ULL << jj);
  }
  mask[((size_t)(b * RSTRIDE) + i) * ROWW + jb] = word;
  if (jb == ib) diag[(size_t)b * RSTRIDE + i] = word;   // packed diagonal word
}

// ---------------- seq NMS v10: readlane chain, prefetched diag -----------
// R12 postmortem: the chain's diag s_loads (64 u64 > SGPR budget) were
// batched in pairs and sunk into the chain -> ~32 serialized ~200cyc SMEM
// loads/chunk = 6.4k cyc, matching the measured floor. v10: wave 0 holds
// the chunk's 64 diag words as ONE coalesced vector load (lane ii = D[ii]),
// prefetched a chunk ahead; the chain consumes them via readlane (VALU,
// compile-time lane index, no memory latency). Fold/barrier structure = R12.
__global__ __launch_bounds__(512) void seq_nms_kernel(
    const u64* __restrict__ mask, const u64* __restrict__ diag,
    const int* __restrict__ valid,
    const float4* __restrict__ boxes, const float* __restrict__ scores,
    float* __restrict__ out) {
  int b = blockIdx.x;
  int tid = threadIdx.x;
  int wid = tid >> 6, lane = tid & 63, lw = lane & 31, hf = lane >> 5;
  __shared__ u64 partial[16];
  __shared__ u64 keepbLDS;
  __shared__ u64 vbufLDS[NCHUNK];
  __shared__ u64 kbits_s[NCHUNK];
  __shared__ int chunkoff[NCHUNK];
  __shared__ int keeplist[PRE];
  __shared__ int Ksh;

  if (tid < 16) partial[tid] = 0ULL;
  if (wid == 0) {
    for (int c = 0; c < NCHUNK; ++c) {
      int q = c * 64 + lane;
      int v = (q < PRE) ? valid[b * RSTRIDE + q] : 0;
      u64 bl = __ballot(v != 0);
      if (lane == 0) vbufLDS[c] = bl;
    }
  }
  __syncthreads();

  const u64* base = mask + (size_t)b * RSTRIDE * ROWW;
  const u64* dg = diag + (size_t)b * RSTRIDE;

  u64 rem = 0ULL;
  u64 Dv = 0ULL;
  if (wid == 0) Dv = dg[lane];   // chunk 0 diag, lane ii holds D[ii]
  int rb0 = wid * 8 + hf;        // this lane's rows: rb0, rb0+2, rb0+4, rb0+6
  for (int c = 0; c < NCHUNK; ++c) {
    int c0 = c * 64;
    // 4 coalesced loads (512B each), independent of keepb; issued pre-barrier
    u64 t0 = base[(size_t)(c0 + rb0 + 0) * ROWW + lw];
    u64 t1 = base[(size_t)(c0 + rb0 + 2) * ROWW + lw];
    u64 t2 = base[(size_t)(c0 + rb0 + 4) * ROWW + lw];
    u64 t3 = base[(size_t)(c0 + rb0 + 6) * ROWW + lw];
    // prefetch next chunk's diag (use is after two barriers -> stays here)
    u64 Dnext = 0ULL;
    if (wid == 0 && c + 1 < NCHUNK) Dnext = dg[(size_t)(c + 1) * 64 + lane];
    if (wid == 0) {
      // cur = OR of 16 partial slots (uniform VALU), then scalarize
      u64 cv = partial[0];
#pragma unroll
      for (int s = 1; s < 16; ++s) cv |= partial[s];
      u32 clo = (u32)__builtin_amdgcn_readfirstlane((int)(u32)cv);
      u32 chi = (u32)__builtin_amdgcn_readfirstlane((int)(u32)(cv >> 32));
      u64 cl = ((u64)chi << 32) | clo;
      u64 vbv = vbufLDS[c];
      u32 vlo = (u32)__builtin_amdgcn_readfirstlane((int)(u32)vbv);
      u32 vhi = (u32)__builtin_amdgcn_readfirstlane((int)(u32)(vbv >> 32));
      u64 vb = ((u64)vhi << 32) | vlo;
      // serial chain: readlane D (register, no memory) + s_cselect/s_or
      u32 dloA = (u32)Dv, dhiA = (u32)(Dv >> 32);
#pragma unroll
      for (int ii = 0; ii < 64; ++ii) {
        u32 dlo = (u32)__builtin_amdgcn_readlane((int)dloA, ii);
        u32 dhi = (u32)__builtin_amdgcn_readlane((int)dhiA, ii);
        u64 D = ((u64)dhi << 32) | dlo;
        u64 tt = ((~cl & vb) >> ii) & 1ULL;
        cl |= tt ? D : 0ULL;
      }
      u64 keepb = vb & ~cl;
      if (lane == 0) { keepbLDS = keepb; kbits_s[c] = keepb; }
    }
    __syncthreads();
    u64 keepb = keepbLDS;                  // broadcast
    rem |= t0 & (0ULL - ((keepb >> (rb0 + 0)) & 1ULL));
    rem |= t1 & (0ULL - ((keepb >> (rb0 + 2)) & 1ULL));
    rem |= t2 & (0ULL - ((keepb >> (rb0 + 4)) & 1ULL));
    rem |= t3 & (0ULL - ((keepb >> (rb0 + 6)) & 1ULL));
    int nw = (c + 1) & 31;
    if (lw == nw) partial[wid * 2 + hf] = rem;   // cumulative, 16 writers
    __syncthreads();
    Dv = Dnext;
  }

  // compact keep list: wave-0 prefix-scan of per-chunk popcounts
  if (wid == 0) {
    int pc = (lane < NCHUNK) ? (int)__popcll(kbits_s[lane]) : 0;
    int inc = pc;
    for (int d = 1; d < 64; d <<= 1) {
      int n = __shfl_up(inc, d, 64);
      if (lane >= d) inc += n;
    }
    if (lane < NCHUNK) chunkoff[lane] = inc - pc;   // exclusive
    if (lane == NCHUNK - 1) Ksh = inc;
  }
  __syncthreads();
  // scatter: 4 chunks per wave
  for (int c = wid * 4; c < wid * 4 + 4; ++c) {
    u64 word = kbits_s[c];
    if ((word >> lane) & 1ULL) {
      int rank = (int)__popcll(word & ((1ULL << lane) - 1ULL));
      keeplist[chunkoff[c] + rank] = c * 64 + lane;
    }
  }
  __syncthreads();
  int K = Ksh;

  float* rois = out;
  float* probs = out + (size_t)BN * POST * 5;
  for (int r = tid; r < POST; r += 512) {
    float x1 = 0.f, y1 = 0.f, x2 = 0.f, y2 = 0.f, pr = 0.f;
    if (r < K) {
      int i = keeplist[r];
      float4 bb = boxes[b * RSTRIDE + i];
      x1 = bb.x; y1 = bb.y; x2 = bb.z; y2 = bb.w;
      pr = scores[b * RSTRIDE + i];
    }
    size_t ro = (size_t)(b * POST + r) * 5;
    rois[ro + 0] = (float)b;
    rois[ro + 1] = x1; rois[ro + 2] = y1; rois[ro + 3] = x2; rois[ro + 4] = y2;
    probs[b * POST + r] = pr;
  }
}

extern "C" void kernel_launch(void* const* d_in, const int* in_sizes, int n_in,
                              void* d_out, int out_size, void* d_ws, size_t ws_size,
                              hipStream_t stream) {
  const float* cls    = (const float*)d_in[0];
  const float* bbox   = (const float*)d_in[1];
  const float* iminfo = (const float*)d_in[2];
  const float* anch   = (const float*)d_in[3];
  char* ws = (char*)d_ws;
  u32* h1    = (u32*)(ws + OFF_H1);
  u32* h2    = (u32*)(ws + OFF_H2);
  u32* cstar = (u32*)(ws + OFF_CSTAR);
  u32* ccnt  = (u32*)(ws + OFF_CCNT);
  u32* thr   = (u32*)(ws + OFF_THR);
  u64* cand  = (u64*)(ws + OFF_CAND);
  float4* boxes = (float4*)(ws + OFF_BOX);
  float* scores = (float*)(ws + OFF_SCORE);
  int* valid    = (int*)(ws + OFF_VALID);
  u64* mask     = (u64*)(ws + OFF_MASK);
  u64* diag     = (u64*)(ws + OFF_DIAG);
  float* out = (float*)d_out;

  hist1_kernel<<<dim3(HBLK, BN), 256, 0, stream>>>(cls, h1);
  coarse_kernel<<<BN, 256, 0, stream>>>(h1, cstar);
  hist2_kernel<<<dim3(HBLK, BN), 256, 0, stream>>>(cls, cstar, h2);
  fine_kernel<<<BN, 256, 0, stream>>>(h2, cstar, thr, ccnt);
  gather_kernel<<<NTOT / 256, 256, 0, stream>>>(cls, thr, ccnt, cand);
  sort_transform_kernel<<<BN, 1024, 0, stream>>>(cand, ccnt, bbox, iminfo, anch,
                                                 boxes, scores, valid);
  nms_mask_kernel<<<dim3(32, 32, BN), 64, 0, stream>>>(boxes, mask, diag);
  seq_nms_kernel<<<BN, 512, 0, stream>>>(mask, diag, valid, boxes, scores, out);
}

// Round 14
// 250.944 us; speedup vs baseline: 1.4180x; 1.2719x over previous
//
#include <hip/hip_runtime.h>
#include <hip/hip_bf16.h>
#include <math.h>

#define BN 8
#define AN 15
#define HH 100
#define WW 168
#define HW (HH*WW)           // 16800
#define NPI (AN*HW)          // 252000 scores per image
#define NTOT (BN*NPI)        // 2016000
#define PRE 2000
#define POST 1000
#define CAP 4096             // candidate buffer per image (threshold-bucket bound ~3000)
#define ROWW 32              // u64 words per NMS mask row (2000 bits -> 32 words)
#define NCHUNK 32            // ceil(PRE/64)
#define RSTRIDE 2048         // padded per-image row stride
#define EPB 4096             // elements per hist block
#define HBLK 62              // ceil(NPI/EPB)
#define GELEM 2048           // elements per gather block
#define GBLK 124             // ceil(NPI/GELEM)

typedef unsigned int u32;
typedef unsigned long long u64;

// ---- workspace layout (bytes) ----
#define OFF_H1     0            // 507904
#define OFF_H2     507904      // 507904 -> 1015808
#define OFF_CSTAR  1015808     // 1024
#define OFF_CCNT   1016832     // 1024 (zeroed by fine_kernel)
#define OFF_THR    1017856     // 1024
#define OFF_CAND   1018880     // 262144 -> 1281024
#define OFF_BOX    1281024     // 262144 -> 1543168
#define OFF_SCORE  1543168     // 65536  -> 1608704
#define OFF_VALID  1608704     // 65536  -> 1674240
#define OFF_MASK   1674240     // 4194304 -> 5868544
#define OFF_DIAG   5868544     // 131072 -> 5999616 (~6 MB total)

__device__ __forceinline__ u32 fmono(float s) {
  u32 u = __float_as_uint(s);
  return (u & 0x80000000u) ? ~u : (u | 0x80000000u);
}
__device__ __forceinline__ float funmono(u32 m) {
  u32 u = (m & 0x80000000u) ? (m ^ 0x80000000u) : ~m;
  return __uint_as_float(u);
}
__device__ __forceinline__ float areaf(float4 bx) {
  return __fmul_rn(__fadd_rn(__fsub_rn(bx.z, bx.x), 1.0f),
                   __fadd_rn(__fsub_rn(bx.w, bx.y), 1.0f));
}

// phase-1 histogram: 256 coarse buckets (m>>24), LDS-privatized 8-way
// (uniform scores pile ~50% of elements into one coarse bucket -> heavy
// same-address LDS atomic serialization; 8 copies halve it vs 4)
__global__ __launch_bounds__(256) void hist1_kernel(const float* __restrict__ cls,
                                                    u32* __restrict__ h1) {
  __shared__ u32 lh[2048];   // 8 copies x 256 buckets
  int b = blockIdx.y;
  int t = threadIdx.x;
  for (int q = t; q < 2048; q += 256) lh[q] = 0u;
  __syncthreads();
  int start = blockIdx.x * EPB;
  int end = min(start + EPB, NPI);
  const float* p = cls + (size_t)b * NPI;
  u32 copy = ((u32)t & 7u) << 8;
  for (int i = start + t; i < end; i += 256) {
    u32 m = fmono(p[i]);
    atomicAdd(&lh[copy | (m >> 24)], 1u);
  }
  __syncthreads();
  u32 s = 0;
#pragma unroll
  for (int cpy = 0; cpy < 8; ++cpy) s += lh[cpy * 256 + t];
  h1[((size_t)(b * HBLK) + blockIdx.x) * 256 + t] = s;   // unconditional
}

// pick coarse bucket c*: sum rows then suffix scan of 256 coarse counts
__global__ __launch_bounds__(256) void coarse_kernel(const u32* __restrict__ h1,
                                                     u32* __restrict__ cstar) {
  int b = blockIdx.x;
  int t = threadIdx.x;
  __shared__ u32 sfx[256];
  u32 s = 0;
  for (int blk = 0; blk < HBLK; ++blk) s += h1[((size_t)(b * HBLK) + blk) * 256 + t];
  sfx[t] = s;
  __syncthreads();
  for (int d = 1; d < 256; d <<= 1) {
    u32 add = (t + d < 256) ? sfx[t + d] : 0u;
    __syncthreads();
    sfx[t] += add;
    __syncthreads();
  }
  if (t == 0 && sfx[0] < (u32)PRE) { cstar[b * 32] = 0u; cstar[b * 32 + 1] = sfx[1]; }
  if (sfx[t] >= (u32)PRE && (t == 255 || sfx[t + 1] < (u32)PRE)) {
    cstar[b * 32] = (u32)t;
    cstar[b * 32 + 1] = (t == 255) ? 0u : sfx[t + 1];   // count strictly above c*
  }
}

// phase-2 histogram: 256 fine buckets ((m>>16)&0xFF), filtered to m>>24==c*,
// atomic-free per-block rows
__global__ __launch_bounds__(256) void hist2_kernel(const float* __restrict__ cls,
                                                    const u32* __restrict__ cstar,
                                                    u32* __restrict__ h2) {
  __shared__ u32 lh[256];
  int b = blockIdx.y;
  int t = threadIdx.x;
  lh[t] = 0u;
  __syncthreads();
  u32 cs = cstar[b * 32];
  int start = blockIdx.x * EPB;
  int end = min(start + EPB, NPI);
  const float* p = cls + (size_t)b * NPI;
  for (int i = start + t; i < end; i += 256) {
    u32 m = fmono(p[i]);
    if ((m >> 24) == cs) atomicAdd(&lh[(m >> 16) & 0xFFu], 1u);
  }
  __syncthreads();
  h2[((size_t)(b * HBLK) + blockIdx.x) * 256 + t] = lh[t];   // unconditional
}

// final 16-bit threshold: thr16 = (c*<<8) | k*; also zeroes ccnt for gather
__global__ __launch_bounds__(256) void fine_kernel(const u32* __restrict__ h2,
                                                   const u32* __restrict__ cstar,
                                                   u32* __restrict__ thr,
                                                   u32* __restrict__ ccnt) {
  int b = blockIdx.x;
  int t = threadIdx.x;
  __shared__ u32 sfx[256];
  u32 s = 0;
  for (int blk = 0; blk < HBLK; ++blk) s += h2[((size_t)(b * HBLK) + blk) * 256 + t];
  sfx[t] = s;
  __syncthreads();
  for (int d = 1; d < 256; d <<= 1) {
    u32 add = (t + d < 256) ? sfx[t + d] : 0u;
    __syncthreads();
    sfx[t] += add;
    __syncthreads();
  }
  u32 cs = cstar[b * 32], base = cstar[b * 32 + 1];
  if (t == 0 && base + sfx[0] < (u32)PRE) thr[b * 32] = (cs << 8);
  if (base + sfx[t] >= (u32)PRE && (t == 255 || base + sfx[t + 1] < (u32)PRE))
    thr[b * 32] = (cs << 8) | (u32)t;
  if (t == 32) ccnt[b * 32] = 0u;    // re-arm gather's counter each call
}

// ---------------- gather v2: block-aggregated single atomic --------------
// R13 postmortem: gather at 77us, VALUBusy 2.3% -- stall-bound on ~17k
// returning wave-leader atomics to 8 hot cachelines (~2.1k serialized
// round-trips per counter). v2: one block = 2048 elements of ONE image;
// per-thread 8-element pass mask (fixed-index regs), wave shfl-scan,
// LDS wave totals, ONE returning atomic per block (992 total), rank-scatter.
__global__ __launch_bounds__(256) void gather_kernel(
    const float* __restrict__ cls, const u32* __restrict__ thr,
    u32* __restrict__ ccnt, u64* __restrict__ cand) {
  int b = blockIdx.y;
  int t = threadIdx.x;
  int lane = t & 63, wid = t >> 6;
  int base_i = blockIdx.x * GELEM;
  const float* p = cls + (size_t)b * NPI;
  u32 T = thr[b * 32];
  __shared__ int wsum[4];
  __shared__ int wbase[4];
  __shared__ u32 baseSh;

  u32 mv[8];
  u32 flags = 0;
#pragma unroll
  for (int k = 0; k < 8; ++k) {
    int i = base_i + k * 256 + t;
    u32 m = 0;
    bool ok = false;
    if (i < NPI) { m = fmono(p[i]); ok = (m >> 16) >= T; }
    mv[k] = m;
    flags |= ok ? (1u << k) : 0u;
  }
  int ct = (int)__popc(flags);
  // wave inclusive scan of ct
  int inc = ct;
  for (int d = 1; d < 64; d <<= 1) {
    int n = __shfl_up(inc, d, 64);
    if (lane >= d) inc += n;
  }
  int excl = inc - ct;
  if (lane == 63) wsum[wid] = inc;   // wave total
  __syncthreads();
  if (t == 0) {
    int acc = 0;
#pragma unroll
    for (int w = 0; w < 4; ++w) { wbase[w] = acc; acc += wsum[w]; }
    baseSh = acc ? atomicAdd(&ccnt[b * 32], (u32)acc) : 0u;
  }
  __syncthreads();
  if (!flags) return;
  u32 pos0 = baseSh + (u32)wbase[wid] + (u32)excl;
#pragma unroll
  for (int k = 0; k < 8; ++k) {
    if ((flags >> k) & 1u) {
      u32 pos = pos0 + (u32)__popc(flags & ((1u << k) - 1u));
      if (pos < CAP) {
        int i = base_i + k * 256 + t;
        int a = i / HW;
        int hw = i - a * HW;
        u32 ti = (u32)(hw * AN + a);   // transposed flat index (h*W + w)*A + a
        cand[(size_t)b * CAP + pos] = ((u64)mv[k] << 32) | (u32)(~ti);
      }
    }
  }
}

__global__ __launch_bounds__(1024) void sort_transform_kernel(
    const u64* __restrict__ cand, const u32* __restrict__ ccnt,
    const float* __restrict__ bbox, const float* __restrict__ iminfo,
    const float* __restrict__ anch,
    float4* __restrict__ boxes, float* __restrict__ scores, int* __restrict__ valid) {
  __shared__ u64 keys[CAP];   // 32 KB
  int b = blockIdx.x;
  int t = threadIdx.x;
  u32 cnt = ccnt[b * 32];
  if (cnt > CAP) cnt = CAP;
  for (int q = t; q < CAP; q += 1024) keys[q] = (q < (int)cnt) ? cand[(size_t)b * CAP + q] : 0ULL;
  __syncthreads();
  // bitonic sort, descending
  for (u32 k = 2; k <= CAP; k <<= 1) {
    for (u32 j = k >> 1; j > 0; j >>= 1) {
      for (int p = 0; p < CAP / 2 / 1024; ++p) {
        u32 idx = (u32)t + (u32)p * 1024u;           // 0..CAP/2-1
        u32 base = ((idx & ~(j - 1)) << 1) | (idx & (j - 1));
        u32 partner = base + j;
        bool up = ((base & k) == 0);
        u64 A = keys[base], B = keys[partner];
        bool sw = up ? (A < B) : (A > B);
        if (sw) { keys[base] = B; keys[partner] = A; }
      }
      __syncthreads();
    }
  }
  // transform the top PRE
  float im_h = iminfo[b * 3 + 0], im_w = iminfo[b * 3 + 1], im_s = iminfo[b * 3 + 2];
  float wmax = __fsub_rn(im_w, 1.0f), hmax = __fsub_rn(im_h, 1.0f);
  float msz = __fmul_rn(0.0f, im_s);
  const float BCLIP = (float)4.135166556742356;  // log(1000/16)
  for (int q = t; q < PRE; q += 1024) {
    u64 key = keys[q];
    u32 i = ~((u32)key);
    // defensive: pad keys (q >= cnt) decode to i >= NPI -> never dereference
    if (q >= (int)cnt || i >= (u32)NPI) {
      boxes[b * RSTRIDE + q] = make_float4(0.f, 0.f, 0.f, 0.f);
      scores[b * RSTRIDE + q] = 0.f;
      valid[b * RSTRIDE + q] = 0;
      continue;
    }
    float sc = funmono((u32)(key >> 32));
    int a = (int)(i % AN);
    int pp = (int)(i / AN);
    int w = pp % WW;
    int h = pp / WW;
    float sx = (float)(w * 8), sy = (float)(h * 8);
    float ax1 = __fadd_rn(anch[a * 4 + 0], sx);
    float ay1 = __fadd_rn(anch[a * 4 + 1], sy);
    float ax2 = __fadd_rn(anch[a * 4 + 2], sx);
    float ay2 = __fadd_rn(anch[a * 4 + 3], sy);
    float wsA = __fadd_rn(__fsub_rn(ax2, ax1), 1.0f);
    float hsA = __fadd_rn(__fsub_rn(ay2, ay1), 1.0f);
    float cx = __fadd_rn(ax1, __fmul_rn(0.5f, wsA));
    float cy = __fadd_rn(ay1, __fmul_rn(0.5f, hsA));
    const float* dp = bbox + ((size_t)b * (4 * AN) + 4 * a) * HW + (size_t)h * WW + w;
    float dx = dp[0], dy = dp[HW], dwv = dp[2 * HW], dhv = dp[3 * HW];
    dwv = fminf(dwv, BCLIP);
    dhv = fminf(dhv, BCLIP);
    float pcx = __fadd_rn(__fmul_rn(dx, wsA), cx);
    float pcy = __fadd_rn(__fmul_rn(dy, hsA), cy);
    float pw = __fmul_rn((float)exp((double)dwv), wsA);
    float ph = __fmul_rn((float)exp((double)dhv), hsA);
    float hpw = __fmul_rn(0.5f, pw), hph = __fmul_rn(0.5f, ph);
    float x1 = __fsub_rn(pcx, hpw);
    float y1 = __fsub_rn(pcy, hph);
    float x2 = __fsub_rn(__fadd_rn(pcx, hpw), 1.0f);
    float y2 = __fsub_rn(__fadd_rn(pcy, hph), 1.0f);
    x1 = fminf(fmaxf(x1, 0.0f), wmax);
    y1 = fminf(fmaxf(y1, 0.0f), hmax);
    x2 = fminf(fmaxf(x2, 0.0f), wmax);
    y2 = fminf(fmaxf(y2, 0.0f), hmax);
    float ws2 = __fadd_rn(__fsub_rn(x2, x1), 1.0f);
    float hs2 = __fadd_rn(__fsub_rn(y2, y1), 1.0f);
    int v = (ws2 >= msz) && (hs2 >= msz) &&
            (__fadd_rn(x1, __fmul_rn(ws2, 0.5f)) < im_w) &&
            (__fadd_rn(y1, __fmul_rn(hs2, 0.5f)) < im_h);
    boxes[b * RSTRIDE + q] = make_float4(x1, y1, x2, y2);
    scores[b * RSTRIDE + q] = sc;
    valid[b * RSTRIDE + q] = v;
  }
}

__global__ __launch_bounds__(64) void nms_mask_kernel(const float4* __restrict__ boxes,
                                                      u64* __restrict__ mask,
                                                      u64* __restrict__ diag) {
  int jb = blockIdx.x, ib = blockIdx.y, b = blockIdx.z;
  if (jb < ib) return;   // upper triangle only (j > i needed)
  int t = threadIdx.x;
  __shared__ float4 jbox[64];
  __shared__ float jarea[64];
  int jbase = jb * 64;
  int jcount = min(64, PRE - jbase);
  if (t < jcount) {
    float4 bj = boxes[b * RSTRIDE + jbase + t];
    jbox[t] = bj;
    jarea[t] = areaf(bj);
  }
  __syncthreads();
  int i = ib * 64 + t;
  if (i >= PRE) return;
  float4 bi = boxes[b * RSTRIDE + i];
  float ai = areaf(bi);
  u64 word = 0ULL;
  for (int jj = 0; jj < jcount; ++jj) {
    int j = jbase + jj;
    if (j <= i) continue;
    float4 bj = jbox[jj];
    float iw = fmaxf(__fadd_rn(__fsub_rn(fminf(bi.z, bj.z), fmaxf(bi.x, bj.x)), 1.0f), 0.0f);
    float ih = fmaxf(__fadd_rn(__fsub_rn(fminf(bi.w, bj.w), fmaxf(bi.y, bj.y)), 1.0f), 0.0f);
    float inter = __fmul_rn(iw, ih);
    float denom = __fsub_rn(__fadd_rn(ai, jarea[jj]), inter);
    float iou = inter / denom;
    if (iou > 0.7f) word |= (1ULL << jj);
  }
  mask[((size_t)(b * RSTRIDE) + i) * ROWW + jb] = word;
  if (jb == ib) diag[(size_t)b * RSTRIDE + i] = word;   // packed diagonal word
}

// ---------------- seq NMS v10: readlane chain, prefetched diag (R13) -----
__global__ __launch_bounds__(512) void seq_nms_kernel(
    const u64* __restrict__ mask, const u64* __restrict__ diag,
    const int* __restrict__ valid,
    const float4* __restrict__ boxes, const float* __restrict__ scores,
    float* __restrict__ out) {
  int b = blockIdx.x;
  int tid = threadIdx.x;
  int wid = tid >> 6, lane = tid & 63, lw = lane & 31, hf = lane >> 5;
  __shared__ u64 partial[16];
  __shared__ u64 keepbLDS;
  __shared__ u64 vbufLDS[NCHUNK];
  __shared__ u64 kbits_s[NCHUNK];
  __shared__ int chunkoff[NCHUNK];
  __shared__ int keeplist[PRE];
  __shared__ int Ksh;

  if (tid < 16) partial[tid] = 0ULL;
  if (wid == 0) {
    for (int c = 0; c < NCHUNK; ++c) {
      int q = c * 64 + lane;
      int v = (q < PRE) ? valid[b * RSTRIDE + q] : 0;
      u64 bl = __ballot(v != 0);
      if (lane == 0) vbufLDS[c] = bl;
    }
  }
  __syncthreads();

  const u64* base = mask + (size_t)b * RSTRIDE * ROWW;
  const u64* dg = diag + (size_t)b * RSTRIDE;

  u64 rem = 0ULL;
  u64 Dv = 0ULL;
  if (wid == 0) Dv = dg[lane];   // chunk 0 diag, lane ii holds D[ii]
  int rb0 = wid * 8 + hf;        // this lane's rows: rb0, rb0+2, rb0+4, rb0+6
  for (int c = 0; c < NCHUNK; ++c) {
    int c0 = c * 64;
    // 4 coalesced loads (512B each), independent of keepb; issued pre-barrier
    u64 t0 = base[(size_t)(c0 + rb0 + 0) * ROWW + lw];
    u64 t1 = base[(size_t)(c0 + rb0 + 2) * ROWW + lw];
    u64 t2 = base[(size_t)(c0 + rb0 + 4) * ROWW + lw];
    u64 t3 = base[(size_t)(c0 + rb0 + 6) * ROWW + lw];
    // prefetch next chunk's diag (use is after two barriers -> stays here)
    u64 Dnext = 0ULL;
    if (wid == 0 && c + 1 < NCHUNK) Dnext = dg[(size_t)(c + 1) * 64 + lane];
    if (wid == 0) {
      // cur = OR of 16 partial slots (uniform VALU), then scalarize
      u64 cv = partial[0];
#pragma unroll
      for (int s = 1; s < 16; ++s) cv |= partial[s];
      u32 clo = (u32)__builtin_amdgcn_readfirstlane((int)(u32)cv);
      u32 chi = (u32)__builtin_amdgcn_readfirstlane((int)(u32)(cv >> 32));
      u64 cl = ((u64)chi << 32) | clo;
      u64 vbv = vbufLDS[c];
      u32 vlo = (u32)__builtin_amdgcn_readfirstlane((int)(u32)vbv);
      u32 vhi = (u32)__builtin_amdgcn_readfirstlane((int)(u32)(vbv >> 32));
      u64 vb = ((u64)vhi << 32) | vlo;
      // serial chain: readlane D (register, no memory) + s_cselect/s_or
      u32 dloA = (u32)Dv, dhiA = (u32)(Dv >> 32);
#pragma unroll
      for (int ii = 0; ii < 64; ++ii) {
        u32 dlo = (u32)__builtin_amdgcn_readlane((int)dloA, ii);
        u32 dhi = (u32)__builtin_amdgcn_readlane((int)dhiA, ii);
        u64 D = ((u64)dhi << 32) | dlo;
        u64 tt = ((~cl & vb) >> ii) & 1ULL;
        cl |= tt ? D : 0ULL;
      }
      u64 keepb = vb & ~cl;
      if (lane == 0) { keepbLDS = keepb; kbits_s[c] = keepb; }
    }
    __syncthreads();
    u64 keepb = keepbLDS;                  // broadcast
    rem |= t0 & (0ULL - ((keepb >> (rb0 + 0)) & 1ULL));
    rem |= t1 & (0ULL - ((keepb >> (rb0 + 2)) & 1ULL));
    rem |= t2 & (0ULL - ((keepb >> (rb0 + 4)) & 1ULL));
    rem |= t3 & (0ULL - ((keepb >> (rb0 + 6)) & 1ULL));
    int nw = (c + 1) & 31;
    if (lw == nw) partial[wid * 2 + hf] = rem;   // cumulative, 16 writers
    __syncthreads();
    Dv = Dnext;
  }

  // compact keep list: wave-0 prefix-scan of per-chunk popcounts
  if (wid == 0) {
    int pc = (lane < NCHUNK) ? (int)__popcll(kbits_s[lane]) : 0;
    int inc = pc;
    for (int d = 1; d < 64; d <<= 1) {
      int n = __shfl_up(inc, d, 64);
      if (lane >= d) inc += n;
    }
    if (lane < NCHUNK) chunkoff[lane] = inc - pc;   // exclusive
    if (lane == NCHUNK - 1) Ksh = inc;
  }
  __syncthreads();
  // scatter: 4 chunks per wave
  for (int c = wid * 4; c < wid * 4 + 4; ++c) {
    u64 word = kbits_s[c];
    if ((word >> lane) & 1ULL) {
      int rank = (int)__popcll(word & ((1ULL << lane) - 1ULL));
      keeplist[chunkoff[c] + rank] = c * 64 + lane;
    }
  }
  __syncthreads();
  int K = Ksh;

  float* rois = out;
  float* probs = out + (size_t)BN * POST * 5;
  for (int r = tid; r < POST; r += 512) {
    float x1 = 0.f, y1 = 0.f, x2 = 0.f, y2 = 0.f, pr = 0.f;
    if (r < K) {
      int i = keeplist[r];
      float4 bb = boxes[b * RSTRIDE + i];
      x1 = bb.x; y1 = bb.y; x2 = bb.z; y2 = bb.w;
      pr = scores[b * RSTRIDE + i];
    }
    size_t ro = (size_t)(b * POST + r) * 5;
    rois[ro + 0] = (float)b;
    rois[ro + 1] = x1; rois[ro + 2] = y1; rois[ro + 3] = x2; rois[ro + 4] = y2;
    probs[b * POST + r] = pr;
  }
}

extern "C" void kernel_launch(void* const* d_in, const int* in_sizes, int n_in,
                              void* d_out, int out_size, void* d_ws, size_t ws_size,
                              hipStream_t stream) {
  const float* cls    = (const float*)d_in[0];
  const float* bbox   = (const float*)d_in[1];
  const float* iminfo = (const float*)d_in[2];
  const float* anch   = (const float*)d_in[3];
  char* ws = (char*)d_ws;
  u32* h1    = (u32*)(ws + OFF_H1);
  u32* h2    = (u32*)(ws + OFF_H2);
  u32* cstar = (u32*)(ws + OFF_CSTAR);
  u32* ccnt  = (u32*)(ws + OFF_CCNT);
  u32* thr   = (u32*)(ws + OFF_THR);
  u64* cand  = (u64*)(ws + OFF_CAND);
  float4* boxes = (float4*)(ws + OFF_BOX);
  float* scores = (float*)(ws + OFF_SCORE);
  int* valid    = (int*)(ws + OFF_VALID);
  u64* mask     = (u64*)(ws + OFF_MASK);
  u64* diag     = (u64*)(ws + OFF_DIAG);
  float* out = (float*)d_out;

  hist1_kernel<<<dim3(HBLK, BN), 256, 0, stream>>>(cls, h1);
  coarse_kernel<<<BN, 256, 0, stream>>>(h1, cstar);
  hist2_kernel<<<dim3(HBLK, BN), 256, 0, stream>>>(cls, cstar, h2);
  fine_kernel<<<BN, 256, 0, stream>>>(h2, cstar, thr, ccnt);
  gather_kernel<<<dim3(GBLK, BN), 256, 0, stream>>>(cls, thr, ccnt, cand);
  sort_transform_kernel<<<BN, 1024, 0, stream>>>(cand, ccnt, bbox, iminfo, anch,
                                                 boxes, scores, valid);
  nms_mask_kernel<<<dim3(32, 32, BN), 64, 0, stream>>>(boxes, mask, diag);
  seq_nms_kernel<<<BN, 512, 0, stream>>>(mask, diag, valid, boxes, scores, out);
}